// Round 3
// baseline (1724.503 us; speedup 1.0000x reference)
//
#include <hip/hip_runtime.h>
#include <hip/hip_bf16.h>
#include <math.h>

#define D_MODEL 256
#define D_STATE 128
#define D_CONV  4
#define D_INNER 512
#define DT_RANK 16
#define BATCH   16
#define LIMG    196
#define LSEQ    199
#define KTXT    768
#define KIMG    1568
#define KHID    3584

typedef const float* fp32p;

// load 8 consecutive floats (16B aligned) -> 8 floats
__device__ __forceinline__ void load8(const float* p, float* f) {
    float4 a = *reinterpret_cast<const float4*>(p);
    float4 b = *reinterpret_cast<const float4*>(p + 4);
    f[0] = a.x; f[1] = a.y; f[2] = a.z; f[3] = a.w;
    f[4] = b.x; f[5] = b.y; f[6] = b.z; f[7] = b.w;
}

// ---------------- kernel 1: embeddings + pos-encoding -> seq (fp32) ----------
__global__ __launch_bounds__(256) void embed_kernel(
    fp32p text, fp32p img, fp32p firsth, fp32p lasth,
    fp32p pt_w, fp32p pt_b, fp32p pi_w, fp32p pi_b,
    fp32p pf_w, fp32p pf_b, fp32p pl_w, fp32p pl_b,
    float* __restrict__ seq)
{
    __shared__ float in_s[KHID];
    int blk = blockIdx.x;
    int b = blk / LSEQ, l = blk % LSEQ;
    int tid = threadIdx.x;

    const float *src, *w, *bias;
    int K;
    if (l == 0)            { src = text   + (size_t)b*KTXT; w = pt_w; bias = pt_b; K = KTXT; }
    else if (l <= LIMG)    { src = nullptr;                  w = pi_w; bias = pi_b; K = KIMG; }
    else if (l == LIMG+1)  { src = firsth + (size_t)b*KHID; w = pf_w; bias = pf_b; K = KHID; }
    else                   { src = lasth  + (size_t)b*KHID; w = pl_w; bias = pl_b; K = KHID; }

    if (src) {
        for (int k0 = tid*8; k0 < K; k0 += 256*8) {
            float f[8]; load8(src + k0, f);
            #pragma unroll
            for (int j = 0; j < 8; ++j) in_s[k0+j] = f[j];
        }
    } else {
        // img is (B, K=1568, LIMG=196); token l uses column p = l-1
        int p = l - 1;
        const float* ib = img + (size_t)b*KIMG*LIMG + p;
        for (int k = tid; k < K; k += 256) in_s[k] = ib[(size_t)k*LIMG];
    }
    __syncthreads();

    int d = tid;
    const float* wr = w + (size_t)d*K;
    float acc = 0.f;
    for (int k = 0; k < K; k += 8) {
        float f[8]; load8(wr + k, f);
        #pragma unroll
        for (int j = 0; j < 8; ++j) acc = fmaf(f[j], in_s[k+j], acc);
    }
    acc += bias[d];

    // positional encoding: even d -> sin(l*div[d/2]), odd d -> cos(l*div[d/2])
    int i = d >> 1;
    float div = __expf((float)(2*i) * (-9.210340371976184f / 256.0f));
    float ang = (float)l * div;
    acc += (d & 1) ? cosf(ang) : sinf(ang);

    seq[((size_t)b*LSEQ + l)*D_MODEL + d] = acc;
}

// ---------------- kernel 2: in_proj -> x, z ---------------------------------
__global__ __launch_bounds__(256) void inproj_kernel(
    const float* __restrict__ seq, fp32p w,
    float* __restrict__ x_ws, float* __restrict__ z_ws)
{
    __shared__ float s[D_MODEL];
    int blk = blockIdx.x, tid = threadIdx.x;
    s[tid] = seq[(size_t)blk*D_MODEL + tid];
    __syncthreads();

    float acc[4] = {0.f, 0.f, 0.f, 0.f};
    const float* w0 = w + (size_t)tid*D_MODEL;
    for (int k = 0; k < D_MODEL; k += 8) {
        #pragma unroll
        for (int r = 0; r < 4; ++r) {
            float f[8]; load8(w0 + (size_t)r*256*D_MODEL + k, f);
            #pragma unroll
            for (int j = 0; j < 8; ++j) acc[r] = fmaf(f[j], s[k+j], acc[r]);
        }
    }
    // rows tid, tid+256 -> x ; rows tid+512, tid+768 -> z
    x_ws[(size_t)blk*D_INNER + tid]       = acc[0];
    x_ws[(size_t)blk*D_INNER + tid + 256] = acc[1];
    z_ws[(size_t)blk*D_INNER + tid]       = acc[2];
    z_ws[(size_t)blk*D_INNER + tid + 256] = acc[3];
}

// ---------------- kernel 3: causal conv (width 4) + silu --------------------
__global__ __launch_bounds__(256) void conv_kernel(
    const float* __restrict__ x_ws, fp32p conv_w, fp32p conv_b,
    float* __restrict__ xs_ws)
{
    int idx = blockIdx.x*256 + threadIdx.x;     // [0, 3184*512)
    int d  = idx & (D_INNER-1);
    int bl = idx >> 9;
    int b = bl / LSEQ, l = bl % LSEQ;
    float acc = conv_b[d];
    const float* xb = x_ws + (size_t)b*LSEQ*D_INNER + d;
    #pragma unroll
    for (int k = 0; k < D_CONV; ++k) {
        int t = l - (D_CONV-1) + k;
        if (t >= 0) acc = fmaf(xb[(size_t)t*D_INNER], conv_w[d*D_CONV + k], acc);
    }
    float sig = 1.f / (1.f + __expf(-acc));
    xs_ws[idx] = acc * sig;
}

// ---------------- kernel 4: x_proj -> (dt,B,C), dt_proj + softplus -> delta -
__global__ __launch_bounds__(256) void xproj_kernel(
    const float* __restrict__ xs_ws, fp32p xp_w, fp32p dtw, fp32p dtb,
    float* __restrict__ delta_ws, float* __restrict__ Bm_ws, float* __restrict__ Cm_ws)
{
    __shared__ float s[D_INNER];
    __shared__ float dt_s[DT_RANK];
    int blk = blockIdx.x, tid = threadIdx.x;
    s[tid]       = xs_ws[(size_t)blk*D_INNER + tid];
    s[tid + 256] = xs_ws[(size_t)blk*D_INNER + tid + 256];
    __syncthreads();

    // outputs j = tid, and j = 256+tid for tid<16  (272 total)
    {
        int j = tid;
        const float* wr = xp_w + (size_t)j*D_INNER;
        float acc = 0.f;
        for (int k = 0; k < D_INNER; k += 8) {
            float f[8]; load8(wr + k, f);
            #pragma unroll
            for (int q = 0; q < 8; ++q) acc = fmaf(f[q], s[k+q], acc);
        }
        if (j < DT_RANK)                    dt_s[j] = acc;
        else if (j < DT_RANK + D_STATE)     Bm_ws[(size_t)blk*D_STATE + (j - DT_RANK)] = acc;
        else                                Cm_ws[(size_t)blk*D_STATE + (j - DT_RANK - D_STATE)] = acc;
    }
    if (tid < DT_RANK) {
        int j = 256 + tid;  // Cm indices 112..127
        const float* wr = xp_w + (size_t)j*D_INNER;
        float acc = 0.f;
        for (int k = 0; k < D_INNER; k += 8) {
            float f[8]; load8(wr + k, f);
            #pragma unroll
            for (int q = 0; q < 8; ++q) acc = fmaf(f[q], s[k+q], acc);
        }
        Cm_ws[(size_t)blk*D_STATE + (j - DT_RANK - D_STATE)] = acc;
    }
    __syncthreads();

    #pragma unroll
    for (int r = 0; r < 2; ++r) {
        int d = tid + r*256;
        const float* wr = dtw + (size_t)d*DT_RANK;
        float acc = dtb[d];
        float f[8];
        load8(wr, f);
        #pragma unroll
        for (int q = 0; q < 8; ++q) acc = fmaf(f[q], dt_s[q], acc);
        load8(wr + 8, f);
        #pragma unroll
        for (int q = 0; q < 8; ++q) acc = fmaf(f[q], dt_s[8+q], acc);
        float sp = (acc > 20.f) ? acc : log1pf(__expf(acc));
        delta_ws[(size_t)blk*D_INNER + d] = sp;
    }
}

// ---------------- kernel 5: selective scan (one wave per (b,d)) -------------
__global__ __launch_bounds__(256) void scan_kernel(
    const float* __restrict__ delta_ws, const float* __restrict__ xs_ws,
    const float* __restrict__ z_ws, const float* __restrict__ Bm_ws,
    const float* __restrict__ Cm_ws, fp32p A_log, fp32p Dp,
    float* __restrict__ y_ws)
{
    int wid  = blockIdx.x*4 + (threadIdx.x >> 6);   // 8192 waves
    int lane = threadIdx.x & 63;
    int b = wid >> 9;
    int d = wid & (D_INNER-1);

    float A0 = -__expf(A_log[(size_t)d*D_STATE + 2*lane]);
    float A1 = -__expf(A_log[(size_t)d*D_STATE + 2*lane + 1]);
    float Dd = Dp[d];

    const float*  dl = delta_ws + (size_t)b*LSEQ*D_INNER + d;
    const float*  xl = xs_ws    + (size_t)b*LSEQ*D_INNER + d;
    const float*  zl = z_ws     + (size_t)b*LSEQ*D_INNER + d;
    const float2* Bl = (const float2*)(Bm_ws + (size_t)b*LSEQ*D_STATE) + lane;
    const float2* Cl = (const float2*)(Cm_ws + (size_t)b*LSEQ*D_STATE) + lane;
    float*        yl = y_ws     + (size_t)b*LSEQ*D_INNER + d;

    float h0 = 0.f, h1 = 0.f;
    for (int t = 0; t < LSEQ; ++t) {
        float delta = dl[(size_t)t*D_INNER];
        float xv    = xl[(size_t)t*D_INNER];
        float2 Bv = Bl[t*(D_STATE/2)];
        float2 Cv = Cl[t*(D_STATE/2)];
        float dA0 = __expf(delta*A0);
        float dA1 = __expf(delta*A1);
        float du = delta*xv;
        h0 = fmaf(dA0, h0, du*Bv.x);
        h1 = fmaf(dA1, h1, du*Bv.y);
        float p = fmaf(h0, Cv.x, h1*Cv.y);
        #pragma unroll
        for (int m = 32; m >= 1; m >>= 1) p += __shfl_xor(p, m, 64);
        if (lane == 0) {
            float zv = zl[(size_t)t*D_INNER];
            float y = fmaf(xv, Dd, p);
            float sig = 1.f / (1.f + __expf(-zv));
            yl[(size_t)t*D_INNER] = y * (zv * sig);
        }
    }
}

// ---------------- kernel 6: out_proj + residual -> fp32 out -----------------
__global__ __launch_bounds__(256) void outproj_kernel(
    const float* __restrict__ y_ws, fp32p ow,
    const float* __restrict__ seq, float* __restrict__ out)
{
    __shared__ float s[D_INNER];
    int blk = blockIdx.x, tid = threadIdx.x;
    s[tid]       = y_ws[(size_t)blk*D_INNER + tid];
    s[tid + 256] = y_ws[(size_t)blk*D_INNER + tid + 256];
    __syncthreads();

    const float* wr = ow + (size_t)tid*D_INNER;
    float acc = seq[(size_t)blk*D_MODEL + tid];
    for (int k = 0; k < D_INNER; k += 8) {
        float f[8]; load8(wr + k, f);
        #pragma unroll
        for (int q = 0; q < 8; ++q) acc = fmaf(f[q], s[k+q], acc);
    }
    out[(size_t)blk*D_MODEL + tid] = acc;   // fp32 output
}

extern "C" void kernel_launch(void* const* d_in, const int* in_sizes, int n_in,
                              void* d_out, int out_size, void* d_ws, size_t ws_size,
                              hipStream_t stream)
{
    fp32p text   = (fp32p)d_in[0];
    fp32p img    = (fp32p)d_in[1];
    fp32p firsth = (fp32p)d_in[2];
    fp32p lasth  = (fp32p)d_in[3];
    fp32p pt_w   = (fp32p)d_in[4];
    fp32p pt_b   = (fp32p)d_in[5];
    fp32p pi_w   = (fp32p)d_in[6];
    fp32p pi_b   = (fp32p)d_in[7];
    fp32p pf_w   = (fp32p)d_in[8];
    fp32p pf_b   = (fp32p)d_in[9];
    fp32p pl_w   = (fp32p)d_in[10];
    fp32p pl_b   = (fp32p)d_in[11];
    fp32p inp_w  = (fp32p)d_in[12];
    fp32p conv_w = (fp32p)d_in[13];
    fp32p conv_b = (fp32p)d_in[14];
    fp32p xp_w   = (fp32p)d_in[15];
    fp32p dt_w   = (fp32p)d_in[16];
    fp32p dt_b   = (fp32p)d_in[17];
    fp32p A_log  = (fp32p)d_in[18];
    fp32p Dp     = (fp32p)d_in[19];
    fp32p out_w  = (fp32p)d_in[20];

    const size_t N_TOK = (size_t)BATCH * LSEQ;            // 3184
    float* ws       = (float*)d_ws;
    float* seq      = ws;                                  // 3184*256
    float* x_ws     = seq      + N_TOK * D_MODEL;          // 3184*512
    float* z_ws     = x_ws     + N_TOK * D_INNER;
    float* xs_ws    = z_ws     + N_TOK * D_INNER;
    float* delta_ws = xs_ws    + N_TOK * D_INNER;
    float* Bm_ws    = delta_ws + N_TOK * D_INNER;          // 3184*128
    float* Cm_ws    = Bm_ws    + N_TOK * D_STATE;
    float* y_ws     = Cm_ws    + N_TOK * D_STATE;

    embed_kernel<<<(int)N_TOK, 256, 0, stream>>>(
        text, img, firsth, lasth, pt_w, pt_b, pi_w, pi_b,
        pf_w, pf_b, pl_w, pl_b, seq);

    inproj_kernel<<<(int)N_TOK, 256, 0, stream>>>(seq, inp_w, x_ws, z_ws);

    conv_kernel<<<(int)(N_TOK * D_INNER / 256), 256, 0, stream>>>(
        x_ws, conv_w, conv_b, xs_ws);

    xproj_kernel<<<(int)N_TOK, 256, 0, stream>>>(
        xs_ws, xp_w, dt_w, dt_b, delta_ws, Bm_ws, Cm_ws);

    scan_kernel<<<BATCH * D_INNER / 4, 256, 0, stream>>>(
        delta_ws, xs_ws, z_ws, Bm_ws, Cm_ws, A_log, Dp, y_ws);

    outproj_kernel<<<(int)N_TOK, 256, 0, stream>>>(y_ws, out_w, seq, (float*)d_out);
}

// Round 4
// 721.108 us; speedup vs baseline: 2.3915x; 2.3915x over previous
//
#include <hip/hip_runtime.h>
#include <hip/hip_bf16.h>
#include <math.h>

#define D_MODEL 256
#define D_STATE 128
#define D_CONV  4
#define D_INNER 512
#define DT_RANK 16
#define BATCH   16
#define LIMG    196
#define LSEQ    199
#define KTXT    768
#define KIMG    1568
#define KHID    3584
#define N_TOK   (BATCH*LSEQ)     // 3184

typedef const float* fp32p;

// ============================================================================
// Generic tiled GEMM:  C[m][n] = sum_k A[m][k] * W[n][k]   (+ epilogue)
//   TM=64, TN=128, BK template, 256 threads, 4x8 micro-tile.
//   EPI: 0 = plain store, 1 = +bias then softplus, 2 = +resid (residual add)
// ============================================================================
template<int BK, int EPI>
__global__ __launch_bounds__(256) void gemm_kernel(
    const float* __restrict__ A, int lda,
    const float* __restrict__ W, int K,      // W is N x K row-major
    float* __restrict__ C, int ldc,
    int M, int N,
    const float* __restrict__ bias,
    const float* __restrict__ resid)
{
    __shared__ __align__(16) float As[BK][68];    // [k][m], stride 68 => 16B-aligned rows
    __shared__ __align__(16) float Ws[BK][132];   // [k][n]
    const int m0 = blockIdx.x * 64;
    const int n0 = blockIdx.y * 128;
    const int tid = threadIdx.x;
    const int tm = (tid & 15) * 4;
    const int tn = (tid >> 4) * 8;
    constexpr int KQ = BK / 4;

    float acc[4][8];
    #pragma unroll
    for (int i = 0; i < 4; ++i)
        #pragma unroll
        for (int j = 0; j < 8; ++j) acc[i][j] = 0.f;

    for (int k0 = 0; k0 < K; k0 += BK) {
        __syncthreads();
        // stage A tile (64 x BK), transpose to [k][m]
        #pragma unroll
        for (int f = tid; f < 64 * KQ; f += 256) {
            int m = f / KQ, kq = f % KQ;
            float4 v = make_float4(0.f, 0.f, 0.f, 0.f);
            if (m0 + m < M) v = *(const float4*)(A + (size_t)(m0 + m) * lda + k0 + 4 * kq);
            As[4*kq+0][m] = v.x; As[4*kq+1][m] = v.y;
            As[4*kq+2][m] = v.z; As[4*kq+3][m] = v.w;
        }
        // stage W tile (128 x BK), transpose to [k][n]
        #pragma unroll
        for (int f = tid; f < 128 * KQ; f += 256) {
            int n = f / KQ, kq = f % KQ;
            float4 v = make_float4(0.f, 0.f, 0.f, 0.f);
            if (n0 + n < N) v = *(const float4*)(W + (size_t)(n0 + n) * K + k0 + 4 * kq);
            Ws[4*kq+0][n] = v.x; Ws[4*kq+1][n] = v.y;
            Ws[4*kq+2][n] = v.z; Ws[4*kq+3][n] = v.w;
        }
        __syncthreads();
        #pragma unroll
        for (int kk = 0; kk < BK; ++kk) {
            float4 a  = *(const float4*)&As[kk][tm];
            float4 b0 = *(const float4*)&Ws[kk][tn];
            float4 b1 = *(const float4*)&Ws[kk][tn + 4];
            float av[4] = {a.x, a.y, a.z, a.w};
            float bv[8] = {b0.x, b0.y, b0.z, b0.w, b1.x, b1.y, b1.z, b1.w};
            #pragma unroll
            for (int i = 0; i < 4; ++i)
                #pragma unroll
                for (int j = 0; j < 8; ++j)
                    acc[i][j] = fmaf(av[i], bv[j], acc[i][j]);
        }
    }

    #pragma unroll
    for (int i = 0; i < 4; ++i) {
        int m = m0 + tm + i;
        if (m >= M) continue;
        #pragma unroll
        for (int j = 0; j < 8; ++j) {
            int n = n0 + tn + j;
            if (n >= N) continue;
            float v = acc[i][j];
            if (EPI == 1) { v += bias[n]; v = (v > 20.f) ? v : log1pf(__expf(v)); }
            if (EPI == 2) { v += resid[(size_t)m * ldc + n]; }
            C[(size_t)m * ldc + n] = v;
        }
    }
}

// ============================================================================
// img embed GEMM: seq[b, 1+p, d] = sum_k img[b,k,p]*pi_w[d,k] + pi_b[d] + PE
//   A-tile is transpose-free: p (token) is the contiguous dim of img.
//   TM=64 (p), TN=64 (d), BK=32, 4x4 micro-tile.
// ============================================================================
__global__ __launch_bounds__(256) void embed_img_kernel(
    fp32p img, fp32p pi_w, fp32p pi_b, float* __restrict__ seq)
{
    __shared__ __align__(16) float As[32][68];   // [k][p]
    __shared__ __align__(16) float Ws[32][68];   // [k][d]
    const int b  = blockIdx.x >> 2;
    const int p0 = (blockIdx.x & 3) * 64;
    const int n0 = blockIdx.y * 64;
    const int tid = threadIdx.x;
    const int tm = (tid & 15) * 4;
    const int tn = (tid >> 4) * 4;

    float acc[4][4];
    #pragma unroll
    for (int i = 0; i < 4; ++i)
        #pragma unroll
        for (int j = 0; j < 4; ++j) acc[i][j] = 0.f;

    const float* imgb = img + (size_t)b * KIMG * LIMG;

    for (int k0 = 0; k0 < KIMG; k0 += 32) {
        __syncthreads();
        // A tile: 32 k-rows x 64 p, direct float4 (p contiguous)
        #pragma unroll
        for (int f = tid; f < 32 * 16; f += 256) {
            int kk = f >> 4, pq = f & 15;
            int p = p0 + 4 * pq;
            float4 v = make_float4(0.f, 0.f, 0.f, 0.f);
            if (p < LIMG) v = *(const float4*)(imgb + (size_t)(k0 + kk) * LIMG + p);
            *(float4*)&As[kk][4 * pq] = v;
        }
        // W tile: 64 d-rows x 32 k, transpose
        #pragma unroll
        for (int f = tid; f < 64 * 8; f += 256) {
            int n = f >> 3, kq = f & 7;
            float4 v = *(const float4*)(pi_w + (size_t)(n0 + n) * KIMG + k0 + 4 * kq);
            Ws[4*kq+0][n] = v.x; Ws[4*kq+1][n] = v.y;
            Ws[4*kq+2][n] = v.z; Ws[4*kq+3][n] = v.w;
        }
        __syncthreads();
        #pragma unroll
        for (int kk = 0; kk < 32; ++kk) {
            float4 a = *(const float4*)&As[kk][tm];
            float4 bb = *(const float4*)&Ws[kk][tn];
            float av[4] = {a.x, a.y, a.z, a.w};
            float bv[4] = {bb.x, bb.y, bb.z, bb.w};
            #pragma unroll
            for (int i = 0; i < 4; ++i)
                #pragma unroll
                for (int j = 0; j < 4; ++j)
                    acc[i][j] = fmaf(av[i], bv[j], acc[i][j]);
        }
    }

    const float cpe = -9.210340371976184f / 256.0f;
    #pragma unroll
    for (int i = 0; i < 4; ++i) {
        int p = p0 + tm + i;
        if (p >= LIMG) continue;
        int l = p + 1;
        int d0 = n0 + tn;
        float diva = __expf((float)d0 * cpe);
        float divb = __expf((float)(d0 + 2) * cpe);
        float4 o;
        o.x = acc[i][0] + pi_b[d0]     + sinf((float)l * diva);
        o.y = acc[i][1] + pi_b[d0 + 1] + cosf((float)l * diva);
        o.z = acc[i][2] + pi_b[d0 + 2] + sinf((float)l * divb);
        o.w = acc[i][3] + pi_b[d0 + 3] + cosf((float)l * divb);
        *(float4*)(seq + ((size_t)b * LSEQ + l) * D_MODEL + d0) = o;
    }
}

// ============================================================================
// small-token embed (text l=0, first l=197, last l=198): 48 blocks
// ============================================================================
__global__ __launch_bounds__(256) void embed_small_kernel(
    fp32p text, fp32p firsth, fp32p lasth,
    fp32p pt_w, fp32p pt_b, fp32p pf_w, fp32p pf_b, fp32p pl_w, fp32p pl_b,
    float* __restrict__ seq)
{
    __shared__ float in_s[KHID];
    int b = blockIdx.x / 3, c = blockIdx.x % 3;
    int tid = threadIdx.x;

    const float *src, *w, *bias; int K, l;
    if (c == 0)      { src = text   + (size_t)b*KTXT; w = pt_w; bias = pt_b; K = KTXT; l = 0; }
    else if (c == 1) { src = firsth + (size_t)b*KHID; w = pf_w; bias = pf_b; K = KHID; l = LIMG+1; }
    else             { src = lasth  + (size_t)b*KHID; w = pl_w; bias = pl_b; K = KHID; l = LIMG+2; }

    for (int k0 = tid*4; k0 < K; k0 += 256*4)
        *(float4*)&in_s[k0] = *(const float4*)(src + k0);
    __syncthreads();

    int d = tid;
    const float* wr = w + (size_t)d*K;
    float acc = 0.f;
    for (int k = 0; k < K; k += 8) {
        float4 f0 = *(const float4*)(wr + k);
        float4 f1 = *(const float4*)(wr + k + 4);
        acc = fmaf(f0.x, in_s[k+0], acc); acc = fmaf(f0.y, in_s[k+1], acc);
        acc = fmaf(f0.z, in_s[k+2], acc); acc = fmaf(f0.w, in_s[k+3], acc);
        acc = fmaf(f1.x, in_s[k+4], acc); acc = fmaf(f1.y, in_s[k+5], acc);
        acc = fmaf(f1.z, in_s[k+6], acc); acc = fmaf(f1.w, in_s[k+7], acc);
    }
    acc += bias[d];
    const float cpe = -9.210340371976184f / 256.0f;
    float div = __expf((float)(d & ~1) * cpe);
    float ang = (float)l * div;
    acc += (d & 1) ? cosf(ang) : sinf(ang);
    seq[((size_t)b*LSEQ + l)*D_MODEL + d] = acc;
}

// ============================================================================
// causal conv(4) + silu : x from xz_ws (stride 1024), out xs_ws (stride 512)
// ============================================================================
__global__ __launch_bounds__(256) void conv_kernel(
    const float* __restrict__ xz_ws, fp32p conv_w, fp32p conv_b,
    float* __restrict__ xs_ws)
{
    int idx = blockIdx.x*256 + threadIdx.x;     // [0, 3184*512)
    int d  = idx & (D_INNER-1);
    int bl = idx >> 9;
    int b = bl / LSEQ, l = bl % LSEQ;
    float acc = conv_b[d];
    const float* xb = xz_ws + (size_t)b*LSEQ*1024 + d;
    #pragma unroll
    for (int k = 0; k < D_CONV; ++k) {
        int t = l - (D_CONV-1) + k;
        if (t >= 0) acc = fmaf(xb[(size_t)t*1024], conv_w[d*D_CONV + k], acc);
    }
    float sig = 1.f / (1.f + __expf(-acc));
    xs_ws[idx] = acc * sig;
}

// ============================================================================
// selective scan: one wave per (b,d)
// ============================================================================
__global__ __launch_bounds__(256) void scan_kernel(
    const float* __restrict__ delta_ws, const float* __restrict__ xs_ws,
    const float* __restrict__ xz_ws, const float* __restrict__ dbc_ws,
    fp32p A_log, fp32p Dp, float* __restrict__ y_ws)
{
    int wid  = blockIdx.x*4 + (threadIdx.x >> 6);   // 8192 waves
    int lane = threadIdx.x & 63;
    int b = wid >> 9;
    int d = wid & (D_INNER-1);

    float A0 = -__expf(A_log[(size_t)d*D_STATE + 2*lane]);
    float A1 = -__expf(A_log[(size_t)d*D_STATE + 2*lane + 1]);
    float Dd = Dp[d];

    const float* dl  = delta_ws + (size_t)b*LSEQ*D_INNER + d;
    const float* xl  = xs_ws    + (size_t)b*LSEQ*D_INNER + d;
    const float* zl  = xz_ws    + (size_t)b*LSEQ*1024 + 512 + d;
    const float* dbc = dbc_ws   + (size_t)b*LSEQ*272;
    float*       yl  = y_ws     + (size_t)b*LSEQ*D_INNER + d;

    float h0 = 0.f, h1 = 0.f;
    for (int t = 0; t < LSEQ; ++t) {
        float delta = dl[(size_t)t*D_INNER];
        float xv    = xl[(size_t)t*D_INNER];
        float2 Bv = ((const float2*)(dbc + (size_t)t*272 + DT_RANK))[lane];
        float2 Cv = ((const float2*)(dbc + (size_t)t*272 + DT_RANK + D_STATE))[lane];
        float dA0 = __expf(delta*A0);
        float dA1 = __expf(delta*A1);
        float du = delta*xv;
        h0 = fmaf(dA0, h0, du*Bv.x);
        h1 = fmaf(dA1, h1, du*Bv.y);
        float p = fmaf(h0, Cv.x, h1*Cv.y);
        #pragma unroll
        for (int m = 32; m >= 1; m >>= 1) p += __shfl_xor(p, m, 64);
        if (lane == 0) {
            float zv = zl[(size_t)t*1024];
            float y = fmaf(xv, Dd, p);
            float sig = 1.f / (1.f + __expf(-zv));
            yl[(size_t)t*D_INNER] = y * (zv * sig);
        }
    }
}

extern "C" void kernel_launch(void* const* d_in, const int* in_sizes, int n_in,
                              void* d_out, int out_size, void* d_ws, size_t ws_size,
                              hipStream_t stream)
{
    fp32p text   = (fp32p)d_in[0];
    fp32p img    = (fp32p)d_in[1];
    fp32p firsth = (fp32p)d_in[2];
    fp32p lasth  = (fp32p)d_in[3];
    fp32p pt_w   = (fp32p)d_in[4];
    fp32p pt_b   = (fp32p)d_in[5];
    fp32p pi_w   = (fp32p)d_in[6];
    fp32p pi_b   = (fp32p)d_in[7];
    fp32p pf_w   = (fp32p)d_in[8];
    fp32p pf_b   = (fp32p)d_in[9];
    fp32p pl_w   = (fp32p)d_in[10];
    fp32p pl_b   = (fp32p)d_in[11];
    fp32p inp_w  = (fp32p)d_in[12];
    fp32p conv_w = (fp32p)d_in[13];
    fp32p conv_b = (fp32p)d_in[14];
    fp32p xp_w   = (fp32p)d_in[15];
    fp32p dt_w   = (fp32p)d_in[16];
    fp32p dt_b   = (fp32p)d_in[17];
    fp32p A_log  = (fp32p)d_in[18];
    fp32p Dp     = (fp32p)d_in[19];
    fp32p out_w  = (fp32p)d_in[20];

    float* ws       = (float*)d_ws;
    float* seq      = ws;                               // 3184*256
    float* xz_ws    = seq      + (size_t)N_TOK*D_MODEL; // 3184*1024 (x | z)
    float* xs_ws    = xz_ws    + (size_t)N_TOK*1024;    // 3184*512
    float* dbc_ws   = xs_ws    + (size_t)N_TOK*D_INNER; // 3184*272 (dt|B|C)
    float* delta_ws = dbc_ws   + (size_t)N_TOK*272;     // 3184*512
    float* y_ws     = delta_ws + (size_t)N_TOK*D_INNER; // 3184*512

    // 1. embeddings
    embed_small_kernel<<<BATCH*3, 256, 0, stream>>>(
        text, firsth, lasth, pt_w, pt_b, pf_w, pf_b, pl_w, pl_b, seq);
    embed_img_kernel<<<dim3(BATCH*4, 4), 256, 0, stream>>>(img, pi_w, pi_b, seq);

    // 2. in_proj: (3184 x 256) @ (1024 x 256)^T -> xz (ldc=1024)
    gemm_kernel<32, 0><<<dim3(50, 8), 256, 0, stream>>>(
        seq, D_MODEL, inp_w, D_MODEL, xz_ws, 1024, N_TOK, 1024, nullptr, nullptr);

    // 3. conv + silu
    conv_kernel<<<N_TOK*D_INNER/256, 256, 0, stream>>>(xz_ws, conv_w, conv_b, xs_ws);

    // 4. x_proj: (3184 x 512) @ (272 x 512)^T -> dbc (ldc=272)
    gemm_kernel<32, 0><<<dim3(50, 3), 256, 0, stream>>>(
        xs_ws, D_INNER, xp_w, D_INNER, dbc_ws, 272, N_TOK, 272, nullptr, nullptr);

    // 5. dt_proj + softplus: (3184 x 16) @ (512 x 16)^T + b -> delta (ldc=512)
    gemm_kernel<16, 1><<<dim3(50, 4), 256, 0, stream>>>(
        dbc_ws, 272, dt_w, DT_RANK, delta_ws, D_INNER, N_TOK, D_INNER, dt_b, nullptr);

    // 6. scan
    scan_kernel<<<BATCH*D_INNER/4, 256, 0, stream>>>(
        delta_ws, xs_ws, xz_ws, dbc_ws, A_log, Dp, y_ws);

    // 7. out_proj + residual: (3184 x 512) @ (256 x 512)^T + seq -> out
    gemm_kernel<32, 2><<<dim3(50, 2), 256, 0, stream>>>(
        y_ws, D_INNER, out_w, D_INNER, (float*)d_out, D_MODEL, N_TOK, D_MODEL, nullptr, seq);
}

// Round 5
// 647.383 us; speedup vs baseline: 2.6638x; 1.1139x over previous
//
#include <hip/hip_runtime.h>
#include <hip/hip_bf16.h>
#include <math.h>

#define D_MODEL 256
#define D_STATE 128
#define D_CONV  4
#define D_INNER 512
#define DT_RANK 16
#define BATCH   16
#define LIMG    196
#define LSEQ    199
#define KTXT    768
#define KIMG    1568
#define KHID    3584
#define N_TOK   (BATCH*LSEQ)     // 3184

typedef const float* fp32p;

// ============================================================================
// Generic tiled GEMM:  C[m][n] = sum_k A[m][k] * W[n][k]   (+ epilogue)
//   TM=64, TN=128, BK template, 256 threads, 4x8 micro-tile.
//   EPI: 0 = plain store, 1 = +bias then softplus, 2 = +resid (residual add)
// ============================================================================
template<int BK, int EPI>
__global__ __launch_bounds__(256) void gemm_kernel(
    const float* __restrict__ A, int lda,
    const float* __restrict__ W, int K,      // W is N x K row-major
    float* __restrict__ C, int ldc,
    int M, int N,
    const float* __restrict__ bias,
    const float* __restrict__ resid)
{
    __shared__ __align__(16) float As[BK][68];    // [k][m], stride 68 => 16B-aligned rows
    __shared__ __align__(16) float Ws[BK][132];   // [k][n]
    const int m0 = blockIdx.x * 64;
    const int n0 = blockIdx.y * 128;
    const int tid = threadIdx.x;
    const int tm = (tid & 15) * 4;
    const int tn = (tid >> 4) * 8;
    constexpr int KQ = BK / 4;

    float acc[4][8];
    #pragma unroll
    for (int i = 0; i < 4; ++i)
        #pragma unroll
        for (int j = 0; j < 8; ++j) acc[i][j] = 0.f;

    for (int k0 = 0; k0 < K; k0 += BK) {
        __syncthreads();
        // stage A tile (64 x BK), transpose to [k][m]
        #pragma unroll
        for (int f = tid; f < 64 * KQ; f += 256) {
            int m = f / KQ, kq = f % KQ;
            float4 v = make_float4(0.f, 0.f, 0.f, 0.f);
            if (m0 + m < M) v = *(const float4*)(A + (size_t)(m0 + m) * lda + k0 + 4 * kq);
            As[4*kq+0][m] = v.x; As[4*kq+1][m] = v.y;
            As[4*kq+2][m] = v.z; As[4*kq+3][m] = v.w;
        }
        // stage W tile (128 x BK), transpose to [k][n]
        #pragma unroll
        for (int f = tid; f < 128 * KQ; f += 256) {
            int n = f / KQ, kq = f % KQ;
            float4 v = make_float4(0.f, 0.f, 0.f, 0.f);
            if (n0 + n < N) v = *(const float4*)(W + (size_t)(n0 + n) * K + k0 + 4 * kq);
            Ws[4*kq+0][n] = v.x; Ws[4*kq+1][n] = v.y;
            Ws[4*kq+2][n] = v.z; Ws[4*kq+3][n] = v.w;
        }
        __syncthreads();
        #pragma unroll
        for (int kk = 0; kk < BK; ++kk) {
            float4 a  = *(const float4*)&As[kk][tm];
            float4 b0 = *(const float4*)&Ws[kk][tn];
            float4 b1 = *(const float4*)&Ws[kk][tn + 4];
            float av[4] = {a.x, a.y, a.z, a.w};
            float bv[8] = {b0.x, b0.y, b0.z, b0.w, b1.x, b1.y, b1.z, b1.w};
            #pragma unroll
            for (int i = 0; i < 4; ++i)
                #pragma unroll
                for (int j = 0; j < 8; ++j)
                    acc[i][j] = fmaf(av[i], bv[j], acc[i][j]);
        }
    }

    #pragma unroll
    for (int i = 0; i < 4; ++i) {
        int m = m0 + tm + i;
        if (m >= M) continue;
        #pragma unroll
        for (int j = 0; j < 8; ++j) {
            int n = n0 + tn + j;
            if (n >= N) continue;
            float v = acc[i][j];
            if (EPI == 1) { v += bias[n]; v = (v > 20.f) ? v : log1pf(__expf(v)); }
            if (EPI == 2) { v += resid[(size_t)m * ldc + n]; }
            C[(size_t)m * ldc + n] = v;
        }
    }
}

// ============================================================================
// img embed GEMM: seq[b, 1+p, d] = sum_k img[b,k,p]*pi_w[d,k] + pi_b[d] + PE
//   TM=64 (p), TN=64 (d), BK=32, 4x4 micro-tile. A transpose-free.
// ============================================================================
__global__ __launch_bounds__(256) void embed_img_kernel(
    fp32p img, fp32p pi_w, fp32p pi_b, float* __restrict__ seq)
{
    __shared__ __align__(16) float As[32][68];   // [k][p]
    __shared__ __align__(16) float Ws[32][68];   // [k][d]
    const int b  = blockIdx.x >> 2;
    const int p0 = (blockIdx.x & 3) * 64;
    const int n0 = blockIdx.y * 64;
    const int tid = threadIdx.x;
    const int tm = (tid & 15) * 4;
    const int tn = (tid >> 4) * 4;

    float acc[4][4];
    #pragma unroll
    for (int i = 0; i < 4; ++i)
        #pragma unroll
        for (int j = 0; j < 4; ++j) acc[i][j] = 0.f;

    const float* imgb = img + (size_t)b * KIMG * LIMG;

    for (int k0 = 0; k0 < KIMG; k0 += 32) {
        __syncthreads();
        #pragma unroll
        for (int f = tid; f < 32 * 16; f += 256) {
            int kk = f >> 4, pq = f & 15;
            int p = p0 + 4 * pq;
            float4 v = make_float4(0.f, 0.f, 0.f, 0.f);
            if (p < LIMG) v = *(const float4*)(imgb + (size_t)(k0 + kk) * LIMG + p);
            *(float4*)&As[kk][4 * pq] = v;
        }
        #pragma unroll
        for (int f = tid; f < 64 * 8; f += 256) {
            int n = f >> 3, kq = f & 7;
            float4 v = *(const float4*)(pi_w + (size_t)(n0 + n) * KIMG + k0 + 4 * kq);
            Ws[4*kq+0][n] = v.x; Ws[4*kq+1][n] = v.y;
            Ws[4*kq+2][n] = v.z; Ws[4*kq+3][n] = v.w;
        }
        __syncthreads();
        #pragma unroll
        for (int kk = 0; kk < 32; ++kk) {
            float4 a = *(const float4*)&As[kk][tm];
            float4 bb = *(const float4*)&Ws[kk][tn];
            float av[4] = {a.x, a.y, a.z, a.w};
            float bv[4] = {bb.x, bb.y, bb.z, bb.w};
            #pragma unroll
            for (int i = 0; i < 4; ++i)
                #pragma unroll
                for (int j = 0; j < 4; ++j)
                    acc[i][j] = fmaf(av[i], bv[j], acc[i][j]);
        }
    }

    const float cpe = -9.210340371976184f / 256.0f;
    #pragma unroll
    for (int i = 0; i < 4; ++i) {
        int p = p0 + tm + i;
        if (p >= LIMG) continue;
        int l = p + 1;
        int d0 = n0 + tn;
        float diva = __expf((float)d0 * cpe);
        float divb = __expf((float)(d0 + 2) * cpe);
        float4 o;
        o.x = acc[i][0] + pi_b[d0]     + sinf((float)l * diva);
        o.y = acc[i][1] + pi_b[d0 + 1] + cosf((float)l * diva);
        o.z = acc[i][2] + pi_b[d0 + 2] + sinf((float)l * divb);
        o.w = acc[i][3] + pi_b[d0 + 3] + cosf((float)l * divb);
        *(float4*)(seq + ((size_t)b * LSEQ + l) * D_MODEL + d0) = o;
    }
}

// ============================================================================
// small-token embed (text l=0, first l=197, last l=198): 48 blocks
// ============================================================================
__global__ __launch_bounds__(256) void embed_small_kernel(
    fp32p text, fp32p firsth, fp32p lasth,
    fp32p pt_w, fp32p pt_b, fp32p pf_w, fp32p pf_b, fp32p pl_w, fp32p pl_b,
    float* __restrict__ seq)
{
    __shared__ float in_s[KHID];
    int b = blockIdx.x / 3, c = blockIdx.x % 3;
    int tid = threadIdx.x;

    const float *src, *w, *bias; int K, l;
    if (c == 0)      { src = text   + (size_t)b*KTXT; w = pt_w; bias = pt_b; K = KTXT; l = 0; }
    else if (c == 1) { src = firsth + (size_t)b*KHID; w = pf_w; bias = pf_b; K = KHID; l = LIMG+1; }
    else             { src = lasth  + (size_t)b*KHID; w = pl_w; bias = pl_b; K = KHID; l = LIMG+2; }

    for (int k0 = tid*4; k0 < K; k0 += 256*4)
        *(float4*)&in_s[k0] = *(const float4*)(src + k0);
    __syncthreads();

    int d = tid;
    const float* wr = w + (size_t)d*K;
    float acc = 0.f;
    for (int k = 0; k < K; k += 8) {
        float4 f0 = *(const float4*)(wr + k);
        float4 f1 = *(const float4*)(wr + k + 4);
        acc = fmaf(f0.x, in_s[k+0], acc); acc = fmaf(f0.y, in_s[k+1], acc);
        acc = fmaf(f0.z, in_s[k+2], acc); acc = fmaf(f0.w, in_s[k+3], acc);
        acc = fmaf(f1.x, in_s[k+4], acc); acc = fmaf(f1.y, in_s[k+5], acc);
        acc = fmaf(f1.z, in_s[k+6], acc); acc = fmaf(f1.w, in_s[k+7], acc);
    }
    acc += bias[d];
    const float cpe = -9.210340371976184f / 256.0f;
    float div = __expf((float)(d & ~1) * cpe);
    float ang = (float)l * div;
    acc += (d & 1) ? cosf(ang) : sinf(ang);
    seq[((size_t)b*LSEQ + l)*D_MODEL + d] = acc;
}

// ============================================================================
// causal conv(4) + silu : x from xz_ws (stride 1024), out xs_ws (stride 512)
// ============================================================================
__global__ __launch_bounds__(256) void conv_kernel(
    const float* __restrict__ xz_ws, fp32p conv_w, fp32p conv_b,
    float* __restrict__ xs_ws)
{
    int idx = blockIdx.x*256 + threadIdx.x;     // [0, 3184*512)
    int d  = idx & (D_INNER-1);
    int bl = idx >> 9;
    int b = bl / LSEQ, l = bl % LSEQ;
    float acc = conv_b[d];
    const float* xb = xz_ws + (size_t)b*LSEQ*1024 + d;
    #pragma unroll
    for (int k = 0; k < D_CONV; ++k) {
        int t = l - (D_CONV-1) + k;
        if (t >= 0) acc = fmaf(xb[(size_t)t*1024], conv_w[d*D_CONV + k], acc);
    }
    float sig = 1.f / (1.f + __expf(-acc));
    xs_ws[idx] = acc * sig;
}

// ============================================================================
// selective scan: one wave per 2 channels (b, d0=2k, d1=2k+1)
//   lanes 0..31 own d0 (4 states/lane), lanes 32..63 own d1.
//   5-level butterfly within 32 lanes; t unrolled by 2 with interleaved
//   butterflies to hide ds_swizzle latency.
// ============================================================================
__global__ __launch_bounds__(256) void scan_kernel(
    const float* __restrict__ delta_ws, const float* __restrict__ xs_ws,
    const float* __restrict__ xz_ws, const float* __restrict__ dbc_ws,
    fp32p A_log, fp32p Dp, float* __restrict__ y_ws)
{
    const int wid  = blockIdx.x*4 + (threadIdx.x >> 6);   // 4096 waves
    const int lane = threadIdx.x & 63;
    const int b  = wid >> 8;           // 256 d-pairs per batch
    const int dp = wid & 255;
    const int sl = lane & 31;          // state-group index within half-wave
    const int d  = dp*2 + (lane >> 5); // lanes 0-31: d0, lanes 32-63: d1

    float4 Av = *(const float4*)(A_log + (size_t)d*D_STATE + 4*sl);
    const float A0 = -__expf(Av.x), A1 = -__expf(Av.y);
    const float A2 = -__expf(Av.z), A3 = -__expf(Av.w);
    const float Dd = Dp[d];

    const float* dl  = delta_ws + (size_t)b*LSEQ*D_INNER + d;
    const float* xl  = xs_ws    + (size_t)b*LSEQ*D_INNER + d;
    const float* zl  = xz_ws    + (size_t)b*LSEQ*1024 + 512 + d;
    const float* dbc = dbc_ws   + (size_t)b*LSEQ*272;
    float*       yl  = y_ws     + (size_t)b*LSEQ*D_INNER + d;

    float h0 = 0.f, h1 = 0.f, h2 = 0.f, h3 = 0.f;

    int t = 0;
    for (; t + 1 < LSEQ; t += 2) {
        const float* row_a = dbc + (size_t)t*272;
        const float* row_b = row_a + 272;
        float da = dl[(size_t)t*D_INNER];
        float db = dl[(size_t)(t+1)*D_INNER];
        float xa = xl[(size_t)t*D_INNER];
        float xb = xl[(size_t)(t+1)*D_INNER];
        float4 Ba = *(const float4*)(row_a + DT_RANK + 4*sl);
        float4 Ca = *(const float4*)(row_a + DT_RANK + D_STATE + 4*sl);
        float4 Bb = *(const float4*)(row_b + DT_RANK + 4*sl);
        float4 Cb = *(const float4*)(row_b + DT_RANK + D_STATE + 4*sl);

        // step t
        float du = da * xa;
        h0 = fmaf(__expf(da*A0), h0, du*Ba.x);
        h1 = fmaf(__expf(da*A1), h1, du*Ba.y);
        h2 = fmaf(__expf(da*A2), h2, du*Ba.z);
        h3 = fmaf(__expf(da*A3), h3, du*Ba.w);
        float p0 = fmaf(h0, Ca.x, fmaf(h1, Ca.y, fmaf(h2, Ca.z, h3*Ca.w)));

        // step t+1
        du = db * xb;
        h0 = fmaf(__expf(db*A0), h0, du*Bb.x);
        h1 = fmaf(__expf(db*A1), h1, du*Bb.y);
        h2 = fmaf(__expf(db*A2), h2, du*Bb.z);
        h3 = fmaf(__expf(db*A3), h3, du*Bb.w);
        float p1 = fmaf(h0, Cb.x, fmaf(h1, Cb.y, fmaf(h2, Cb.z, h3*Cb.w)));

        // two independent 5-level butterflies (within 32 lanes), interleaved
        #pragma unroll
        for (int m = 16; m >= 1; m >>= 1) {
            float q0 = __shfl_xor(p0, m, 64);
            float q1 = __shfl_xor(p1, m, 64);
            p0 += q0; p1 += q1;
        }

        if (sl == 0) {   // lanes 0 and 32 hold the sums for d0/d1
            float za = zl[(size_t)t*1024];
            float zb = zl[(size_t)(t+1)*1024];
            float ya = fmaf(xa, Dd, p0) * (za / (1.f + __expf(-za)));
            float yb = fmaf(xb, Dd, p1) * (zb / (1.f + __expf(-zb)));
            yl[(size_t)t*D_INNER]     = ya;
            yl[(size_t)(t+1)*D_INNER] = yb;
        }
    }
    // last step (t = 198)
    {
        const float* row = dbc + (size_t)t*272;
        float da = dl[(size_t)t*D_INNER];
        float xa = xl[(size_t)t*D_INNER];
        float4 Ba = *(const float4*)(row + DT_RANK + 4*sl);
        float4 Ca = *(const float4*)(row + DT_RANK + D_STATE + 4*sl);
        float du = da * xa;
        h0 = fmaf(__expf(da*A0), h0, du*Ba.x);
        h1 = fmaf(__expf(da*A1), h1, du*Ba.y);
        h2 = fmaf(__expf(da*A2), h2, du*Ba.z);
        h3 = fmaf(__expf(da*A3), h3, du*Ba.w);
        float p0 = fmaf(h0, Ca.x, fmaf(h1, Ca.y, fmaf(h2, Ca.z, h3*Ca.w)));
        #pragma unroll
        for (int m = 16; m >= 1; m >>= 1) p0 += __shfl_xor(p0, m, 64);
        if (sl == 0) {
            float za = zl[(size_t)t*1024];
            float ya = fmaf(xa, Dd, p0) * (za / (1.f + __expf(-za)));
            yl[(size_t)t*D_INNER] = ya;
        }
    }
}

extern "C" void kernel_launch(void* const* d_in, const int* in_sizes, int n_in,
                              void* d_out, int out_size, void* d_ws, size_t ws_size,
                              hipStream_t stream)
{
    fp32p text   = (fp32p)d_in[0];
    fp32p img    = (fp32p)d_in[1];
    fp32p firsth = (fp32p)d_in[2];
    fp32p lasth  = (fp32p)d_in[3];
    fp32p pt_w   = (fp32p)d_in[4];
    fp32p pt_b   = (fp32p)d_in[5];
    fp32p pi_w   = (fp32p)d_in[6];
    fp32p pi_b   = (fp32p)d_in[7];
    fp32p pf_w   = (fp32p)d_in[8];
    fp32p pf_b   = (fp32p)d_in[9];
    fp32p pl_w   = (fp32p)d_in[10];
    fp32p pl_b   = (fp32p)d_in[11];
    fp32p inp_w  = (fp32p)d_in[12];
    fp32p conv_w = (fp32p)d_in[13];
    fp32p conv_b = (fp32p)d_in[14];
    fp32p xp_w   = (fp32p)d_in[15];
    fp32p dt_w   = (fp32p)d_in[16];
    fp32p dt_b   = (fp32p)d_in[17];
    fp32p A_log  = (fp32p)d_in[18];
    fp32p Dp     = (fp32p)d_in[19];
    fp32p out_w  = (fp32p)d_in[20];

    float* ws       = (float*)d_ws;
    float* seq      = ws;                               // 3184*256
    float* xz_ws    = seq      + (size_t)N_TOK*D_MODEL; // 3184*1024 (x | z)
    float* xs_ws    = xz_ws    + (size_t)N_TOK*1024;    // 3184*512
    float* dbc_ws   = xs_ws    + (size_t)N_TOK*D_INNER; // 3184*272 (dt|B|C)
    float* delta_ws = dbc_ws   + (size_t)N_TOK*272;     // 3184*512
    float* y_ws     = delta_ws + (size_t)N_TOK*D_INNER; // 3184*512

    // 1. embeddings
    embed_small_kernel<<<BATCH*3, 256, 0, stream>>>(
        text, firsth, lasth, pt_w, pt_b, pf_w, pf_b, pl_w, pl_b, seq);
    embed_img_kernel<<<dim3(BATCH*4, 4), 256, 0, stream>>>(img, pi_w, pi_b, seq);

    // 2. in_proj: (3184 x 256) @ (1024 x 256)^T -> xz (ldc=1024)
    gemm_kernel<32, 0><<<dim3(50, 8), 256, 0, stream>>>(
        seq, D_MODEL, inp_w, D_MODEL, xz_ws, 1024, N_TOK, 1024, nullptr, nullptr);

    // 3. conv + silu
    conv_kernel<<<N_TOK*D_INNER/256, 256, 0, stream>>>(xz_ws, conv_w, conv_b, xs_ws);

    // 4. x_proj: (3184 x 512) @ (272 x 512)^T -> dbc (ldc=272)
    gemm_kernel<32, 0><<<dim3(50, 3), 256, 0, stream>>>(
        xs_ws, D_INNER, xp_w, D_INNER, dbc_ws, 272, N_TOK, 272, nullptr, nullptr);

    // 5. dt_proj + softplus: (3184 x 16) @ (512 x 16)^T + b -> delta (ldc=512)
    gemm_kernel<16, 1><<<dim3(50, 4), 256, 0, stream>>>(
        dbc_ws, 272, dt_w, DT_RANK, delta_ws, D_INNER, N_TOK, D_INNER, dt_b, nullptr);

    // 6. scan (4096 waves, 2 channels/wave)
    scan_kernel<<<BATCH*D_INNER/8, 256, 0, stream>>>(
        delta_ws, xs_ws, xz_ws, dbc_ws, A_log, Dp, y_ws);

    // 7. out_proj + residual: (3184 x 512) @ (256 x 512)^T + seq -> out
    gemm_kernel<32, 2><<<dim3(50, 2), 256, 0, stream>>>(
        y_ws, D_INNER, out_w, D_INNER, (float*)d_out, D_MODEL, N_TOK, D_MODEL, nullptr, seq);
}

// Round 6
// 524.440 us; speedup vs baseline: 3.2883x; 1.2344x over previous
//
#include <hip/hip_runtime.h>
#include <hip/hip_bf16.h>
#include <math.h>

#define D_MODEL 256
#define D_STATE 128
#define D_CONV  4
#define D_INNER 512
#define DT_RANK 16
#define BATCH   16
#define LIMG    196
#define LSEQ    199
#define KTXT    768
#define KIMG    1568
#define KHID    3584
#define N_TOK   (BATCH*LSEQ)     // 3184
#define N_IMG   (BATCH*LIMG)     // 3136

typedef const float* fp32p;

// ============================================================================
// Generic tiled GEMM:  C[m][n] = sum_k A[m][k] * W[n][k]   (+ epilogue)
//   TM=32, TN=64, BK template, 256 threads, 2x4 micro-tile.
//   gridDim.z = K-split; each z writes partial to C + z*M*ldc.
//   EPI: 0 = plain store, 1 = +bias then softplus
// ============================================================================
template<int BK, int EPI>
__global__ __launch_bounds__(256) void gemm_kernel(
    const float* __restrict__ A, int lda,
    const float* __restrict__ W, int K,      // W is N x K row-major
    float* __restrict__ C, int ldc,
    int M, int N,
    const float* __restrict__ bias)
{
    __shared__ __align__(16) float As[BK][36];    // [k][m]
    __shared__ __align__(16) float Ws[BK][68];    // [k][n]
    const int m0 = blockIdx.x * 32;
    const int n0 = blockIdx.y * 64;
    const int tid = threadIdx.x;
    const int tm = (tid & 15) * 2;
    const int tn = (tid >> 4) * 4;
    constexpr int KQ = BK / 4;

    const int kper = K / (int)gridDim.z;
    const int k0s = blockIdx.z * kper;
    if (gridDim.z > 1) C += (size_t)blockIdx.z * M * ldc;

    float acc[2][4];
    #pragma unroll
    for (int i = 0; i < 2; ++i)
        #pragma unroll
        for (int j = 0; j < 4; ++j) acc[i][j] = 0.f;

    for (int k0 = k0s; k0 < k0s + kper; k0 += BK) {
        __syncthreads();
        // stage A tile (32 x BK) -> [k][m]
        for (int f = tid; f < 8 * BK; f += 256) {
            int m = f / KQ, kq = f % KQ;
            float4 v = make_float4(0.f, 0.f, 0.f, 0.f);
            if (m0 + m < M) v = *(const float4*)(A + (size_t)(m0 + m) * lda + k0 + 4 * kq);
            As[4*kq+0][m] = v.x; As[4*kq+1][m] = v.y;
            As[4*kq+2][m] = v.z; As[4*kq+3][m] = v.w;
        }
        // stage W tile (64 x BK) -> [k][n]
        for (int f = tid; f < 16 * BK; f += 256) {
            int n = f / KQ, kq = f % KQ;
            float4 v = make_float4(0.f, 0.f, 0.f, 0.f);
            if (n0 + n < N) v = *(const float4*)(W + (size_t)(n0 + n) * K + k0 + 4 * kq);
            Ws[4*kq+0][n] = v.x; Ws[4*kq+1][n] = v.y;
            Ws[4*kq+2][n] = v.z; Ws[4*kq+3][n] = v.w;
        }
        __syncthreads();
        #pragma unroll
        for (int kk = 0; kk < BK; ++kk) {
            float2 a = *(const float2*)&As[kk][tm];
            float4 bb = *(const float4*)&Ws[kk][tn];
            float av[2] = {a.x, a.y};
            float bv[4] = {bb.x, bb.y, bb.z, bb.w};
            #pragma unroll
            for (int i = 0; i < 2; ++i)
                #pragma unroll
                for (int j = 0; j < 4; ++j)
                    acc[i][j] = fmaf(av[i], bv[j], acc[i][j]);
        }
    }

    #pragma unroll
    for (int i = 0; i < 2; ++i) {
        int m = m0 + tm + i;
        if (m >= M) continue;
        #pragma unroll
        for (int j = 0; j < 4; ++j) {
            int n = n0 + tn + j;
            if (n >= N) continue;
            float v = acc[i][j];
            if (EPI == 1) { v += bias[n]; v = (v > 20.f) ? v : log1pf(__expf(v)); }
            C[(size_t)m * ldc + n] = v;
        }
    }
}

// ============================================================================
// img embed GEMM partials: epart[z][b*196+p][d] = sum_{k in split z} img*W
//   TM=32 (p), TN=64 (d), BK=28, K-split 2 (784 each), 2x4 micro-tile.
// ============================================================================
__global__ __launch_bounds__(256) void embed_img_kernel(
    fp32p img, fp32p pi_w, float* __restrict__ epart)
{
    __shared__ __align__(16) float As[28][36];   // [k][p]
    __shared__ __align__(16) float Ws[28][68];   // [k][d]
    const int b  = blockIdx.x / 7;
    const int p0 = (blockIdx.x % 7) * 32;
    const int n0 = blockIdx.y * 64;
    const int tid = threadIdx.x;
    const int tm = (tid & 15) * 2;
    const int tn = (tid >> 4) * 4;
    const int k0s = blockIdx.z * 784;

    float acc[2][4];
    #pragma unroll
    for (int i = 0; i < 2; ++i)
        #pragma unroll
        for (int j = 0; j < 4; ++j) acc[i][j] = 0.f;

    const float* imgb = img + (size_t)b * KIMG * LIMG;

    for (int k0 = k0s; k0 < k0s + 784; k0 += 28) {
        __syncthreads();
        // A tile: 28 k-rows x 32 p, direct float4 (p contiguous)
        for (int f = tid; f < 28 * 8; f += 256) {
            int kk = f >> 3, pq = f & 7;
            int p = p0 + 4 * pq;
            float4 v = make_float4(0.f, 0.f, 0.f, 0.f);
            if (p < LIMG) v = *(const float4*)(imgb + (size_t)(k0 + kk) * LIMG + p);
            *(float4*)&As[kk][4 * pq] = v;
        }
        // W tile: 64 d-rows x 28 k, transpose
        for (int f = tid; f < 64 * 7; f += 256) {
            int n = f / 7, kq = f % 7;
            float4 v = *(const float4*)(pi_w + (size_t)(n0 + n) * KIMG + k0 + 4 * kq);
            Ws[4*kq+0][n] = v.x; Ws[4*kq+1][n] = v.y;
            Ws[4*kq+2][n] = v.z; Ws[4*kq+3][n] = v.w;
        }
        __syncthreads();
        #pragma unroll
        for (int kk = 0; kk < 28; ++kk) {
            float2 a = *(const float2*)&As[kk][tm];
            float4 bb = *(const float4*)&Ws[kk][tn];
            float av[2] = {a.x, a.y};
            float bv[4] = {bb.x, bb.y, bb.z, bb.w};
            #pragma unroll
            for (int i = 0; i < 2; ++i)
                #pragma unroll
                for (int j = 0; j < 4; ++j)
                    acc[i][j] = fmaf(av[i], bv[j], acc[i][j]);
        }
    }

    float* ep = epart + (size_t)blockIdx.z * N_IMG * D_MODEL;
    #pragma unroll
    for (int i = 0; i < 2; ++i) {
        int p = p0 + tm + i;
        if (p >= LIMG) continue;
        float4 o = make_float4(acc[i][0], acc[i][1], acc[i][2], acc[i][3]);
        *(float4*)(ep + ((size_t)b * LIMG + p) * D_MODEL + n0 + tn) = o;
    }
}

// ============================================================================
// img finish: seq[b][1+p][d] = ep0 + ep1 + pi_b[d] + PE(1+p, d)
// ============================================================================
__global__ __launch_bounds__(256) void img_finish_kernel(
    const float* __restrict__ epart, fp32p pi_b, float* __restrict__ seq)
{
    int idx = (blockIdx.x * 256 + threadIdx.x) * 4;   // [0, 3136*256)
    int d0  = idx & (D_MODEL - 1);
    int row = idx >> 8;                                // b*196 + p
    int b = row / LIMG, p = row % LIMG;
    int l = p + 1;

    float4 a = *(const float4*)(epart + idx);
    float4 c = *(const float4*)(epart + (size_t)N_IMG * D_MODEL + idx);
    float4 bb = *(const float4*)(pi_b + d0);

    const float cpe = -9.210340371976184f / 256.0f;
    float diva = __expf((float)d0 * cpe);
    float divb = __expf((float)(d0 + 2) * cpe);
    float4 o;
    o.x = a.x + c.x + bb.x + sinf((float)l * diva);
    o.y = a.y + c.y + bb.y + cosf((float)l * diva);
    o.z = a.z + c.z + bb.z + sinf((float)l * divb);
    o.w = a.w + c.w + bb.w + cosf((float)l * divb);
    *(float4*)(seq + ((size_t)b * LSEQ + l) * D_MODEL + d0) = o;
}

// ============================================================================
// out finish: d_out = seq + op0 + op1
// ============================================================================
__global__ __launch_bounds__(256) void out_finish_kernel(
    const float* __restrict__ seq, const float* __restrict__ opart,
    float* __restrict__ out)
{
    int idx = (blockIdx.x * 256 + threadIdx.x) * 4;   // [0, 3184*256)
    float4 s = *(const float4*)(seq + idx);
    float4 a = *(const float4*)(opart + idx);
    float4 c = *(const float4*)(opart + (size_t)N_TOK * D_MODEL + idx);
    float4 o;
    o.x = s.x + a.x + c.x; o.y = s.y + a.y + c.y;
    o.z = s.z + a.z + c.z; o.w = s.w + a.w + c.w;
    *(float4*)(out + idx) = o;
}

// ============================================================================
// small-token embed (text l=0, first l=197, last l=198): 48 blocks
// ============================================================================
__global__ __launch_bounds__(256) void embed_small_kernel(
    fp32p text, fp32p firsth, fp32p lasth,
    fp32p pt_w, fp32p pt_b, fp32p pf_w, fp32p pf_b, fp32p pl_w, fp32p pl_b,
    float* __restrict__ seq)
{
    __shared__ float in_s[KHID];
    int b = blockIdx.x / 3, c = blockIdx.x % 3;
    int tid = threadIdx.x;

    const float *src, *w, *bias; int K, l;
    if (c == 0)      { src = text   + (size_t)b*KTXT; w = pt_w; bias = pt_b; K = KTXT; l = 0; }
    else if (c == 1) { src = firsth + (size_t)b*KHID; w = pf_w; bias = pf_b; K = KHID; l = LIMG+1; }
    else             { src = lasth  + (size_t)b*KHID; w = pl_w; bias = pl_b; K = KHID; l = LIMG+2; }

    for (int k0 = tid*4; k0 < K; k0 += 256*4)
        *(float4*)&in_s[k0] = *(const float4*)(src + k0);
    __syncthreads();

    int d = tid;
    const float* wr = w + (size_t)d*K;
    float acc = 0.f;
    for (int k = 0; k < K; k += 8) {
        float4 f0 = *(const float4*)(wr + k);
        float4 f1 = *(const float4*)(wr + k + 4);
        acc = fmaf(f0.x, in_s[k+0], acc); acc = fmaf(f0.y, in_s[k+1], acc);
        acc = fmaf(f0.z, in_s[k+2], acc); acc = fmaf(f0.w, in_s[k+3], acc);
        acc = fmaf(f1.x, in_s[k+4], acc); acc = fmaf(f1.y, in_s[k+5], acc);
        acc = fmaf(f1.z, in_s[k+6], acc); acc = fmaf(f1.w, in_s[k+7], acc);
    }
    acc += bias[d];
    const float cpe = -9.210340371976184f / 256.0f;
    float div = __expf((float)(d & ~1) * cpe);
    float ang = (float)l * div;
    acc += (d & 1) ? cosf(ang) : sinf(ang);
    seq[((size_t)b*LSEQ + l)*D_MODEL + d] = acc;
}

// ============================================================================
// causal conv(4) + silu : x from xz_ws (stride 1024), out xs_ws (stride 512)
// ============================================================================
__global__ __launch_bounds__(256) void conv_kernel(
    const float* __restrict__ xz_ws, fp32p conv_w, fp32p conv_b,
    float* __restrict__ xs_ws)
{
    int idx = blockIdx.x*256 + threadIdx.x;     // [0, 3184*512)
    int d  = idx & (D_INNER-1);
    int bl = idx >> 9;
    int b = bl / LSEQ, l = bl % LSEQ;
    float acc = conv_b[d];
    const float* xb = xz_ws + (size_t)b*LSEQ*1024 + d;
    #pragma unroll
    for (int k = 0; k < D_CONV; ++k) {
        int t = l - (D_CONV-1) + k;
        if (t >= 0) acc = fmaf(xb[(size_t)t*1024], conv_w[d*D_CONV + k], acc);
    }
    float sig = 1.f / (1.f + __expf(-acc));
    xs_ws[idx] = acc * sig;
}

// ============================================================================
// selective scan: one wave per 2 channels (b, d0=2k, d1=2k+1)
// ============================================================================
__global__ __launch_bounds__(256) void scan_kernel(
    const float* __restrict__ delta_ws, const float* __restrict__ xs_ws,
    const float* __restrict__ xz_ws, const float* __restrict__ dbc_ws,
    fp32p A_log, fp32p Dp, float* __restrict__ y_ws)
{
    const int wid  = blockIdx.x*4 + (threadIdx.x >> 6);   // 4096 waves
    const int lane = threadIdx.x & 63;
    const int b  = wid >> 8;
    const int dp = wid & 255;
    const int sl = lane & 31;
    const int d  = dp*2 + (lane >> 5);

    float4 Av = *(const float4*)(A_log + (size_t)d*D_STATE + 4*sl);
    const float A0 = -__expf(Av.x), A1 = -__expf(Av.y);
    const float A2 = -__expf(Av.z), A3 = -__expf(Av.w);
    const float Dd = Dp[d];

    const float* dl  = delta_ws + (size_t)b*LSEQ*D_INNER + d;
    const float* xl  = xs_ws    + (size_t)b*LSEQ*D_INNER + d;
    const float* zl  = xz_ws    + (size_t)b*LSEQ*1024 + 512 + d;
    const float* dbc = dbc_ws   + (size_t)b*LSEQ*272;
    float*       yl  = y_ws     + (size_t)b*LSEQ*D_INNER + d;

    float h0 = 0.f, h1 = 0.f, h2 = 0.f, h3 = 0.f;

    int t = 0;
    for (; t + 1 < LSEQ; t += 2) {
        const float* row_a = dbc + (size_t)t*272;
        const float* row_b = row_a + 272;
        float da = dl[(size_t)t*D_INNER];
        float db = dl[(size_t)(t+1)*D_INNER];
        float xa = xl[(size_t)t*D_INNER];
        float xb = xl[(size_t)(t+1)*D_INNER];
        float4 Ba = *(const float4*)(row_a + DT_RANK + 4*sl);
        float4 Ca = *(const float4*)(row_a + DT_RANK + D_STATE + 4*sl);
        float4 Bb = *(const float4*)(row_b + DT_RANK + 4*sl);
        float4 Cb = *(const float4*)(row_b + DT_RANK + D_STATE + 4*sl);

        float du = da * xa;
        h0 = fmaf(__expf(da*A0), h0, du*Ba.x);
        h1 = fmaf(__expf(da*A1), h1, du*Ba.y);
        h2 = fmaf(__expf(da*A2), h2, du*Ba.z);
        h3 = fmaf(__expf(da*A3), h3, du*Ba.w);
        float p0 = fmaf(h0, Ca.x, fmaf(h1, Ca.y, fmaf(h2, Ca.z, h3*Ca.w)));

        du = db * xb;
        h0 = fmaf(__expf(db*A0), h0, du*Bb.x);
        h1 = fmaf(__expf(db*A1), h1, du*Bb.y);
        h2 = fmaf(__expf(db*A2), h2, du*Bb.z);
        h3 = fmaf(__expf(db*A3), h3, du*Bb.w);
        float p1 = fmaf(h0, Cb.x, fmaf(h1, Cb.y, fmaf(h2, Cb.z, h3*Cb.w)));

        #pragma unroll
        for (int m = 16; m >= 1; m >>= 1) {
            float q0 = __shfl_xor(p0, m, 64);
            float q1 = __shfl_xor(p1, m, 64);
            p0 += q0; p1 += q1;
        }

        if (sl == 0) {
            float za = zl[(size_t)t*1024];
            float zb = zl[(size_t)(t+1)*1024];
            float ya = fmaf(xa, Dd, p0) * (za / (1.f + __expf(-za)));
            float yb = fmaf(xb, Dd, p1) * (zb / (1.f + __expf(-zb)));
            yl[(size_t)t*D_INNER]     = ya;
            yl[(size_t)(t+1)*D_INNER] = yb;
        }
    }
    {
        const float* row = dbc + (size_t)t*272;
        float da = dl[(size_t)t*D_INNER];
        float xa = xl[(size_t)t*D_INNER];
        float4 Ba = *(const float4*)(row + DT_RANK + 4*sl);
        float4 Ca = *(const float4*)(row + DT_RANK + D_STATE + 4*sl);
        float du = da * xa;
        h0 = fmaf(__expf(da*A0), h0, du*Ba.x);
        h1 = fmaf(__expf(da*A1), h1, du*Ba.y);
        h2 = fmaf(__expf(da*A2), h2, du*Ba.z);
        h3 = fmaf(__expf(da*A3), h3, du*Ba.w);
        float p0 = fmaf(h0, Ca.x, fmaf(h1, Ca.y, fmaf(h2, Ca.z, h3*Ca.w)));
        #pragma unroll
        for (int m = 16; m >= 1; m >>= 1) p0 += __shfl_xor(p0, m, 64);
        if (sl == 0) {
            float za = zl[(size_t)t*1024];
            float ya = fmaf(xa, Dd, p0) * (za / (1.f + __expf(-za)));
            yl[(size_t)t*D_INNER] = ya;
        }
    }
}

extern "C" void kernel_launch(void* const* d_in, const int* in_sizes, int n_in,
                              void* d_out, int out_size, void* d_ws, size_t ws_size,
                              hipStream_t stream)
{
    fp32p text   = (fp32p)d_in[0];
    fp32p img    = (fp32p)d_in[1];
    fp32p firsth = (fp32p)d_in[2];
    fp32p lasth  = (fp32p)d_in[3];
    fp32p pt_w   = (fp32p)d_in[4];
    fp32p pt_b   = (fp32p)d_in[5];
    fp32p pi_w   = (fp32p)d_in[6];
    fp32p pi_b   = (fp32p)d_in[7];
    fp32p pf_w   = (fp32p)d_in[8];
    fp32p pf_b   = (fp32p)d_in[9];
    fp32p pl_w   = (fp32p)d_in[10];
    fp32p pl_b   = (fp32p)d_in[11];
    fp32p inp_w  = (fp32p)d_in[12];
    fp32p conv_w = (fp32p)d_in[13];
    fp32p conv_b = (fp32p)d_in[14];
    fp32p xp_w   = (fp32p)d_in[15];
    fp32p dt_w   = (fp32p)d_in[16];
    fp32p dt_b   = (fp32p)d_in[17];
    fp32p A_log  = (fp32p)d_in[18];
    fp32p Dp     = (fp32p)d_in[19];
    fp32p out_w  = (fp32p)d_in[20];

    float* ws       = (float*)d_ws;
    float* seq      = ws;                               // 3184*256
    float* xz_ws    = seq      + (size_t)N_TOK*D_MODEL; // 3184*1024 (x | z)
    float* xs_ws    = xz_ws    + (size_t)N_TOK*1024;    // 3184*512
    float* dbc_ws   = xs_ws    + (size_t)N_TOK*D_INNER; // 3184*272 (dt|B|C)
    float* delta_ws = dbc_ws   + (size_t)N_TOK*272;     // 3184*512
    float* y_ws     = delta_ws + (size_t)N_TOK*D_INNER; // 3184*512
    float* epart    = y_ws     + (size_t)N_TOK*D_INNER; // 2*3136*256
    float* opart    = epart    + (size_t)2*N_IMG*D_MODEL; // 2*3184*256

    // 1. embeddings
    embed_small_kernel<<<BATCH*3, 256, 0, stream>>>(
        text, firsth, lasth, pt_w, pt_b, pf_w, pf_b, pl_w, pl_b, seq);
    embed_img_kernel<<<dim3(BATCH*7, 4, 2), 256, 0, stream>>>(img, pi_w, epart);
    img_finish_kernel<<<N_IMG*D_MODEL/1024, 256, 0, stream>>>(epart, pi_b, seq);

    // 2. in_proj: (3184 x 256) @ (1024 x 256)^T -> xz (ldc=1024)
    gemm_kernel<32, 0><<<dim3(100, 16), 256, 0, stream>>>(
        seq, D_MODEL, inp_w, D_MODEL, xz_ws, 1024, N_TOK, 1024, nullptr);

    // 3. conv + silu
    conv_kernel<<<N_TOK*D_INNER/256, 256, 0, stream>>>(xz_ws, conv_w, conv_b, xs_ws);

    // 4. x_proj: (3184 x 512) @ (272 x 512)^T -> dbc (ldc=272)
    gemm_kernel<32, 0><<<dim3(100, 5), 256, 0, stream>>>(
        xs_ws, D_INNER, xp_w, D_INNER, dbc_ws, 272, N_TOK, 272, nullptr);

    // 5. dt_proj + softplus: (3184 x 16) @ (512 x 16)^T + b -> delta (ldc=512)
    gemm_kernel<16, 1><<<dim3(100, 8), 256, 0, stream>>>(
        dbc_ws, 272, dt_w, DT_RANK, delta_ws, D_INNER, N_TOK, D_INNER, dt_b);

    // 6. scan (4096 waves, 2 channels/wave)
    scan_kernel<<<BATCH*D_INNER/8, 256, 0, stream>>>(
        delta_ws, xs_ws, xz_ws, dbc_ws, A_log, Dp, y_ws);

    // 7. out_proj (K-split 2 -> partials), then finish: d_out = seq + p0 + p1
    gemm_kernel<32, 0><<<dim3(100, 4, 2), 256, 0, stream>>>(
        y_ws, D_INNER, out_w, D_INNER, opart, D_MODEL, N_TOK, D_MODEL, nullptr);
    out_finish_kernel<<<N_TOK*D_MODEL/1024, 256, 0, stream>>>(seq, opart, (float*)d_out);
}

// Round 7
// 519.312 us; speedup vs baseline: 3.3207x; 1.0099x over previous
//
#include <hip/hip_runtime.h>
#include <hip/hip_bf16.h>
#include <math.h>

#define D_MODEL 256
#define D_STATE 128
#define D_CONV  4
#define D_INNER 512
#define DT_RANK 16
#define BATCH   16
#define LIMG    196
#define LSEQ    199
#define KTXT    768
#define KIMG    1568
#define KHID    3584
#define N_TOK   (BATCH*LSEQ)     // 3184
#define N_IMG   (BATCH*LIMG)     // 3136

typedef const float* fp32p;

// ============================================================================
// Generic tiled GEMM:  C = A @ W^T   (+ epilogue)
//   TM=32, TN=64, 256 threads, 2x4 micro-tile.
//   AT: A stored K-major (A[k*lda + m]) -> transpose-free A staging
//   CT: store C transposed (C[n*ldc + m])
//   gridDim.z = K-split; each z writes partial to C + z*M*ldc (CT=0 only).
//   EPI: 0 = plain store, 1 = +bias then softplus
// ============================================================================
template<int BK, int EPI, int AT, int CT>
__global__ __launch_bounds__(256) void gemm_kernel(
    const float* __restrict__ A, int lda,
    const float* __restrict__ W, int K,      // W is N x K row-major
    float* __restrict__ C, int ldc,
    int M, int N,
    const float* __restrict__ bias)
{
    __shared__ __align__(16) float As[BK][36];    // [k][m]
    __shared__ __align__(16) float Ws[BK][68];    // [k][n]
    const int m0 = blockIdx.x * 32;
    const int n0 = blockIdx.y * 64;
    const int tid = threadIdx.x;
    const int tm = (tid & 15) * 2;
    const int tn = (tid >> 4) * 4;
    constexpr int KQ = BK / 4;

    const int kper = K / (int)gridDim.z;
    const int k0s = blockIdx.z * kper;
    if (!CT && gridDim.z > 1) C += (size_t)blockIdx.z * M * ldc;

    float acc[2][4];
    #pragma unroll
    for (int i = 0; i < 2; ++i)
        #pragma unroll
        for (int j = 0; j < 4; ++j) acc[i][j] = 0.f;

    for (int k0 = k0s; k0 < k0s + kper; k0 += BK) {
        __syncthreads();
        if (AT) {
            // A[k][m]: direct float4 copy, no transpose
            for (int f = tid; f < 8 * BK; f += 256) {
                int kk = f >> 3, mq = f & 7;
                int m = m0 + 4 * mq;
                float4 v = make_float4(0.f, 0.f, 0.f, 0.f);
                if (m < M) v = *(const float4*)(A + (size_t)(k0 + kk) * lda + m);
                *(float4*)&As[kk][4 * mq] = v;
            }
        } else {
            // A[m][k]: transpose to [k][m]
            for (int f = tid; f < 8 * BK; f += 256) {
                int m = f / KQ, kq = f % KQ;
                float4 v = make_float4(0.f, 0.f, 0.f, 0.f);
                if (m0 + m < M) v = *(const float4*)(A + (size_t)(m0 + m) * lda + k0 + 4 * kq);
                As[4*kq+0][m] = v.x; As[4*kq+1][m] = v.y;
                As[4*kq+2][m] = v.z; As[4*kq+3][m] = v.w;
            }
        }
        // stage W tile (64 x BK) -> [k][n]
        for (int f = tid; f < 16 * BK; f += 256) {
            int n = f / KQ, kq = f % KQ;
            float4 v = make_float4(0.f, 0.f, 0.f, 0.f);
            if (n0 + n < N) v = *(const float4*)(W + (size_t)(n0 + n) * K + k0 + 4 * kq);
            Ws[4*kq+0][n] = v.x; Ws[4*kq+1][n] = v.y;
            Ws[4*kq+2][n] = v.z; Ws[4*kq+3][n] = v.w;
        }
        __syncthreads();
        #pragma unroll
        for (int kk = 0; kk < BK; ++kk) {
            float2 a = *(const float2*)&As[kk][tm];
            float4 bb = *(const float4*)&Ws[kk][tn];
            float av[2] = {a.x, a.y};
            float bv[4] = {bb.x, bb.y, bb.z, bb.w};
            #pragma unroll
            for (int i = 0; i < 2; ++i)
                #pragma unroll
                for (int j = 0; j < 4; ++j)
                    acc[i][j] = fmaf(av[i], bv[j], acc[i][j]);
        }
    }

    if (CT) {
        int m = m0 + tm;
        #pragma unroll
        for (int j = 0; j < 4; ++j) {
            int n = n0 + tn + j;
            if (n >= N) continue;
            float v0 = acc[0][j], v1 = acc[1][j];
            if (EPI == 1) {
                v0 += bias[n]; v0 = (v0 > 20.f) ? v0 : log1pf(__expf(v0));
                v1 += bias[n]; v1 = (v1 > 20.f) ? v1 : log1pf(__expf(v1));
            }
            if (m + 1 < M) {
                float2 st = make_float2(v0, v1);
                *(float2*)(C + (size_t)n * ldc + m) = st;
            } else if (m < M) {
                C[(size_t)n * ldc + m] = v0;
            }
        }
    } else {
        #pragma unroll
        for (int i = 0; i < 2; ++i) {
            int m = m0 + tm + i;
            if (m >= M) continue;
            #pragma unroll
            for (int j = 0; j < 4; ++j) {
                int n = n0 + tn + j;
                if (n >= N) continue;
                float v = acc[i][j];
                if (EPI == 1) { v += bias[n]; v = (v > 20.f) ? v : log1pf(__expf(v)); }
                C[(size_t)m * ldc + n] = v;
            }
        }
    }
}

// ============================================================================
// img embed GEMM partials: epart[z][b*196+p][d] = sum_{k in split z} img*W
// ============================================================================
__global__ __launch_bounds__(256) void embed_img_kernel(
    fp32p img, fp32p pi_w, float* __restrict__ epart)
{
    __shared__ __align__(16) float As[28][36];   // [k][p]
    __shared__ __align__(16) float Ws[28][68];   // [k][d]
    const int b  = blockIdx.x / 7;
    const int p0 = (blockIdx.x % 7) * 32;
    const int n0 = blockIdx.y * 64;
    const int tid = threadIdx.x;
    const int tm = (tid & 15) * 2;
    const int tn = (tid >> 4) * 4;
    const int k0s = blockIdx.z * 784;

    float acc[2][4];
    #pragma unroll
    for (int i = 0; i < 2; ++i)
        #pragma unroll
        for (int j = 0; j < 4; ++j) acc[i][j] = 0.f;

    const float* imgb = img + (size_t)b * KIMG * LIMG;

    for (int k0 = k0s; k0 < k0s + 784; k0 += 28) {
        __syncthreads();
        for (int f = tid; f < 28 * 8; f += 256) {
            int kk = f >> 3, pq = f & 7;
            int p = p0 + 4 * pq;
            float4 v = make_float4(0.f, 0.f, 0.f, 0.f);
            if (p < LIMG) v = *(const float4*)(imgb + (size_t)(k0 + kk) * LIMG + p);
            *(float4*)&As[kk][4 * pq] = v;
        }
        for (int f = tid; f < 64 * 7; f += 256) {
            int n = f / 7, kq = f % 7;
            float4 v = *(const float4*)(pi_w + (size_t)(n0 + n) * KIMG + k0 + 4 * kq);
            Ws[4*kq+0][n] = v.x; Ws[4*kq+1][n] = v.y;
            Ws[4*kq+2][n] = v.z; Ws[4*kq+3][n] = v.w;
        }
        __syncthreads();
        #pragma unroll
        for (int kk = 0; kk < 28; ++kk) {
            float2 a = *(const float2*)&As[kk][tm];
            float4 bb = *(const float4*)&Ws[kk][tn];
            float av[2] = {a.x, a.y};
            float bv[4] = {bb.x, bb.y, bb.z, bb.w};
            #pragma unroll
            for (int i = 0; i < 2; ++i)
                #pragma unroll
                for (int j = 0; j < 4; ++j)
                    acc[i][j] = fmaf(av[i], bv[j], acc[i][j]);
        }
    }

    float* ep = epart + (size_t)blockIdx.z * N_IMG * D_MODEL;
    #pragma unroll
    for (int i = 0; i < 2; ++i) {
        int p = p0 + tm + i;
        if (p >= LIMG) continue;
        float4 o = make_float4(acc[i][0], acc[i][1], acc[i][2], acc[i][3]);
        *(float4*)(ep + ((size_t)b * LIMG + p) * D_MODEL + n0 + tn) = o;
    }
}

// img finish: seq[b][1+p][d] = ep0 + ep1 + pi_b[d] + PE(1+p, d)
__global__ __launch_bounds__(256) void img_finish_kernel(
    const float* __restrict__ epart, fp32p pi_b, float* __restrict__ seq)
{
    int idx = (blockIdx.x * 256 + threadIdx.x) * 4;
    int d0  = idx & (D_MODEL - 1);
    int row = idx >> 8;
    int b = row / LIMG, p = row % LIMG;
    int l = p + 1;

    float4 a = *(const float4*)(epart + idx);
    float4 c = *(const float4*)(epart + (size_t)N_IMG * D_MODEL + idx);
    float4 bb = *(const float4*)(pi_b + d0);

    const float cpe = -9.210340371976184f / 256.0f;
    float diva = __expf((float)d0 * cpe);
    float divb = __expf((float)(d0 + 2) * cpe);
    float4 o;
    o.x = a.x + c.x + bb.x + sinf((float)l * diva);
    o.y = a.y + c.y + bb.y + cosf((float)l * diva);
    o.z = a.z + c.z + bb.z + sinf((float)l * divb);
    o.w = a.w + c.w + bb.w + cosf((float)l * divb);
    *(float4*)(seq + ((size_t)b * LSEQ + l) * D_MODEL + d0) = o;
}

// out finish: d_out = seq + op0 + op1
__global__ __launch_bounds__(256) void out_finish_kernel(
    const float* __restrict__ seq, const float* __restrict__ opart,
    float* __restrict__ out)
{
    int idx = (blockIdx.x * 256 + threadIdx.x) * 4;
    float4 s = *(const float4*)(seq + idx);
    float4 a = *(const float4*)(opart + idx);
    float4 c = *(const float4*)(opart + (size_t)N_TOK * D_MODEL + idx);
    float4 o;
    o.x = s.x + a.x + c.x; o.y = s.y + a.y + c.y;
    o.z = s.z + a.z + c.z; o.w = s.w + a.w + c.w;
    *(float4*)(out + idx) = o;
}

// small-token embed (text l=0, first l=197, last l=198): 48 blocks
__global__ __launch_bounds__(256) void embed_small_kernel(
    fp32p text, fp32p firsth, fp32p lasth,
    fp32p pt_w, fp32p pt_b, fp32p pf_w, fp32p pf_b, fp32p pl_w, fp32p pl_b,
    float* __restrict__ seq)
{
    __shared__ float in_s[KHID];
    int b = blockIdx.x / 3, c = blockIdx.x % 3;
    int tid = threadIdx.x;

    const float *src, *w, *bias; int K, l;
    if (c == 0)      { src = text   + (size_t)b*KTXT; w = pt_w; bias = pt_b; K = KTXT; l = 0; }
    else if (c == 1) { src = firsth + (size_t)b*KHID; w = pf_w; bias = pf_b; K = KHID; l = LIMG+1; }
    else             { src = lasth  + (size_t)b*KHID; w = pl_w; bias = pl_b; K = KHID; l = LIMG+2; }

    for (int k0 = tid*4; k0 < K; k0 += 256*4)
        *(float4*)&in_s[k0] = *(const float4*)(src + k0);
    __syncthreads();

    int d = tid;
    const float* wr = w + (size_t)d*K;
    float acc = 0.f;
    for (int k = 0; k < K; k += 8) {
        float4 f0 = *(const float4*)(wr + k);
        float4 f1 = *(const float4*)(wr + k + 4);
        acc = fmaf(f0.x, in_s[k+0], acc); acc = fmaf(f0.y, in_s[k+1], acc);
        acc = fmaf(f0.z, in_s[k+2], acc); acc = fmaf(f0.w, in_s[k+3], acc);
        acc = fmaf(f1.x, in_s[k+4], acc); acc = fmaf(f1.y, in_s[k+5], acc);
        acc = fmaf(f1.z, in_s[k+6], acc); acc = fmaf(f1.w, in_s[k+7], acc);
    }
    acc += bias[d];
    const float cpe = -9.210340371976184f / 256.0f;
    float div = __expf((float)(d & ~1) * cpe);
    float ang = (float)l * div;
    acc += (d & 1) ? cosf(ang) : sinf(ang);
    seq[((size_t)b*LSEQ + l)*D_MODEL + d] = acc;
}

// ============================================================================
// causal conv(4) + silu over transposed layout:
//   x = xz_T[d][m] (d<512), out xs_T[d][m], m = b*199+t
// ============================================================================
__global__ __launch_bounds__(256) void conv_t_kernel(
    const float* __restrict__ xz_T, fp32p conv_w, fp32p conv_b,
    float* __restrict__ xs_T)
{
    int m = blockIdx.x * 256 + threadIdx.x;
    if (m >= N_TOK) return;
    int d = blockIdx.y;
    int t = m % LSEQ;
    const float* xr = xz_T + (size_t)d * N_TOK;
    float w0 = conv_w[d*D_CONV + 0], w1 = conv_w[d*D_CONV + 1];
    float w2 = conv_w[d*D_CONV + 2], w3 = conv_w[d*D_CONV + 3];
    float acc = conv_b[d];
    if (t >= 3) {
        acc = fmaf(xr[m-3], w0, acc); acc = fmaf(xr[m-2], w1, acc);
        acc = fmaf(xr[m-1], w2, acc); acc = fmaf(xr[m],   w3, acc);
    } else {
        if (t >= 3) acc = fmaf(xr[m-3], w0, acc);
        if (t >= 2) acc = fmaf(xr[m-2], w1, acc);
        if (t >= 1) acc = fmaf(xr[m-1], w2, acc);
        acc = fmaf(xr[m], w3, acc);
    }
    float sig = 1.f / (1.f + __expf(-acc));
    xs_T[(size_t)d * N_TOK + m] = acc * sig;
}

// ============================================================================
// selective scan: one wave per 2 channels; delta/x/z/y in [d][token] layout
// ============================================================================
__global__ __launch_bounds__(256) void scan_kernel(
    const float* __restrict__ delta_T, const float* __restrict__ xs_T,
    const float* __restrict__ xz_T, const float* __restrict__ dbc_ws,
    fp32p A_log, fp32p Dp, float* __restrict__ y_T)
{
    const int wid  = blockIdx.x*4 + (threadIdx.x >> 6);   // 4096 waves
    const int lane = threadIdx.x & 63;
    const int b  = wid >> 8;
    const int dp = wid & 255;
    const int sl = lane & 31;
    const int d  = dp*2 + (lane >> 5);

    float4 Av = *(const float4*)(A_log + (size_t)d*D_STATE + 4*sl);
    const float A0 = -__expf(Av.x), A1 = -__expf(Av.y);
    const float A2 = -__expf(Av.z), A3 = -__expf(Av.w);
    const float Dd = Dp[d];

    const float* dl  = delta_T + (size_t)d*N_TOK + b*LSEQ;
    const float* xl  = xs_T    + (size_t)d*N_TOK + b*LSEQ;
    const float* zl  = xz_T    + (size_t)(D_INNER + d)*N_TOK + b*LSEQ;
    const float* dbc = dbc_ws  + (size_t)b*LSEQ*272;
    float*       yl  = y_T     + (size_t)d*N_TOK + b*LSEQ;

    float h0 = 0.f, h1 = 0.f, h2 = 0.f, h3 = 0.f;

    int t = 0;
    for (; t + 1 < LSEQ; t += 2) {
        const float* row_a = dbc + (size_t)t*272;
        const float* row_b = row_a + 272;
        float da = dl[t],   db = dl[t+1];
        float xa = xl[t],   xb = xl[t+1];
        float4 Ba = *(const float4*)(row_a + DT_RANK + 4*sl);
        float4 Ca = *(const float4*)(row_a + DT_RANK + D_STATE + 4*sl);
        float4 Bb = *(const float4*)(row_b + DT_RANK + 4*sl);
        float4 Cb = *(const float4*)(row_b + DT_RANK + D_STATE + 4*sl);

        float du = da * xa;
        h0 = fmaf(__expf(da*A0), h0, du*Ba.x);
        h1 = fmaf(__expf(da*A1), h1, du*Ba.y);
        h2 = fmaf(__expf(da*A2), h2, du*Ba.z);
        h3 = fmaf(__expf(da*A3), h3, du*Ba.w);
        float p0 = fmaf(h0, Ca.x, fmaf(h1, Ca.y, fmaf(h2, Ca.z, h3*Ca.w)));

        du = db * xb;
        h0 = fmaf(__expf(db*A0), h0, du*Bb.x);
        h1 = fmaf(__expf(db*A1), h1, du*Bb.y);
        h2 = fmaf(__expf(db*A2), h2, du*Bb.z);
        h3 = fmaf(__expf(db*A3), h3, du*Bb.w);
        float p1 = fmaf(h0, Cb.x, fmaf(h1, Cb.y, fmaf(h2, Cb.z, h3*Cb.w)));

        #pragma unroll
        for (int mm = 16; mm >= 1; mm >>= 1) {
            float q0 = __shfl_xor(p0, mm, 64);
            float q1 = __shfl_xor(p1, mm, 64);
            p0 += q0; p1 += q1;
        }

        if (sl == 0) {
            float za = zl[t], zb = zl[t+1];
            float ya = fmaf(xa, Dd, p0) * (za / (1.f + __expf(-za)));
            float yb = fmaf(xb, Dd, p1) * (zb / (1.f + __expf(-zb)));
            yl[t]   = ya;
            yl[t+1] = yb;
        }
    }
    {
        const float* row = dbc + (size_t)t*272;
        float da = dl[t];
        float xa = xl[t];
        float4 Ba = *(const float4*)(row + DT_RANK + 4*sl);
        float4 Ca = *(const float4*)(row + DT_RANK + D_STATE + 4*sl);
        float du = da * xa;
        h0 = fmaf(__expf(da*A0), h0, du*Ba.x);
        h1 = fmaf(__expf(da*A1), h1, du*Ba.y);
        h2 = fmaf(__expf(da*A2), h2, du*Ba.z);
        h3 = fmaf(__expf(da*A3), h3, du*Ba.w);
        float p0 = fmaf(h0, Ca.x, fmaf(h1, Ca.y, fmaf(h2, Ca.z, h3*Ca.w)));
        #pragma unroll
        for (int mm = 16; mm >= 1; mm >>= 1) p0 += __shfl_xor(p0, mm, 64);
        if (sl == 0) {
            float za = zl[t];
            float ya = fmaf(xa, Dd, p0) * (za / (1.f + __expf(-za)));
            yl[t] = ya;
        }
    }
}

extern "C" void kernel_launch(void* const* d_in, const int* in_sizes, int n_in,
                              void* d_out, int out_size, void* d_ws, size_t ws_size,
                              hipStream_t stream)
{
    fp32p text   = (fp32p)d_in[0];
    fp32p img    = (fp32p)d_in[1];
    fp32p firsth = (fp32p)d_in[2];
    fp32p lasth  = (fp32p)d_in[3];
    fp32p pt_w   = (fp32p)d_in[4];
    fp32p pt_b   = (fp32p)d_in[5];
    fp32p pi_w   = (fp32p)d_in[6];
    fp32p pi_b   = (fp32p)d_in[7];
    fp32p pf_w   = (fp32p)d_in[8];
    fp32p pf_b   = (fp32p)d_in[9];
    fp32p pl_w   = (fp32p)d_in[10];
    fp32p pl_b   = (fp32p)d_in[11];
    fp32p inp_w  = (fp32p)d_in[12];
    fp32p conv_w = (fp32p)d_in[13];
    fp32p conv_b = (fp32p)d_in[14];
    fp32p xp_w   = (fp32p)d_in[15];
    fp32p dt_w   = (fp32p)d_in[16];
    fp32p dt_b   = (fp32p)d_in[17];
    fp32p A_log  = (fp32p)d_in[18];
    fp32p Dp     = (fp32p)d_in[19];
    fp32p out_w  = (fp32p)d_in[20];

    float* ws      = (float*)d_ws;
    float* seq     = ws;                                   // 3184*256
    float* xz_T    = seq     + (size_t)N_TOK*D_MODEL;      // 1024*3184 (+pad)
    float* xs_T    = xz_T    + (size_t)1024*N_TOK + 16;    // 512*3184 (+pad)
    float* dbc_ws  = xs_T    + (size_t)D_INNER*N_TOK + 16; // 3184*272
    float* delta_T = dbc_ws  + (size_t)N_TOK*272;          // 512*3184 (+pad)
    float* y_T     = delta_T + (size_t)D_INNER*N_TOK + 16; // 512*3184 (+pad)
    float* epart   = y_T     + (size_t)D_INNER*N_TOK + 16; // 2*3136*256
    float* opart   = epart   + (size_t)2*N_IMG*D_MODEL;    // 2*3184*256

    // 1. embeddings
    embed_small_kernel<<<BATCH*3, 256, 0, stream>>>(
        text, firsth, lasth, pt_w, pt_b, pf_w, pf_b, pl_w, pl_b, seq);
    embed_img_kernel<<<dim3(BATCH*7, 4, 2), 256, 0, stream>>>(img, pi_w, epart);
    img_finish_kernel<<<N_IMG*D_MODEL/1024, 256, 0, stream>>>(epart, pi_b, seq);

    // 2. in_proj: (3184 x 256) @ (1024 x 256)^T -> xz_T [1024][3184]
    gemm_kernel<32, 0, 0, 1><<<dim3(100, 16), 256, 0, stream>>>(
        seq, D_MODEL, inp_w, D_MODEL, xz_T, N_TOK, N_TOK, 1024, nullptr);

    // 3. conv + silu over [d][m]
    conv_t_kernel<<<dim3(13, D_INNER), 256, 0, stream>>>(xz_T, conv_w, conv_b, xs_T);

    // 4. x_proj: A = xs_T (K-major), -> dbc token-major [m][272]
    gemm_kernel<32, 0, 1, 0><<<dim3(100, 5), 256, 0, stream>>>(
        xs_T, N_TOK, xp_w, D_INNER, dbc_ws, 272, N_TOK, 272, nullptr);

    // 5. dt_proj + softplus: -> delta_T [512][3184]
    gemm_kernel<16, 1, 0, 1><<<dim3(100, 8), 256, 0, stream>>>(
        dbc_ws, 272, dt_w, DT_RANK, delta_T, N_TOK, N_TOK, D_INNER, dt_b);

    // 6. scan (4096 waves, 2 channels/wave), transposed operands
    scan_kernel<<<BATCH*D_INNER/8, 256, 0, stream>>>(
        delta_T, xs_T, xz_T, dbc_ws, A_log, Dp, y_T);

    // 7. out_proj: A = y_T (K-major), K-split 2 -> partials; finish adds resid
    gemm_kernel<32, 0, 1, 0><<<dim3(100, 4, 2), 256, 0, stream>>>(
        y_T, N_TOK, out_w, D_INNER, opart, D_MODEL, N_TOK, D_MODEL, nullptr);
    out_finish_kernel<<<N_TOK*D_MODEL/1024, 256, 0, stream>>>(seq, opart, (float*)d_out);
}

// Round 8
// 479.816 us; speedup vs baseline: 3.5941x; 1.0823x over previous
//
#include <hip/hip_runtime.h>
#include <hip/hip_bf16.h>
#include <math.h>

#define D_MODEL 256
#define D_STATE 128
#define D_CONV  4
#define D_INNER 512
#define DT_RANK 16
#define BATCH   16
#define LIMG    196
#define LSEQ    199
#define KTXT    768
#define KIMG    1568
#define KHID    3584
#define N_TOK   (BATCH*LSEQ)     // 3184
#define N_IMG   (BATCH*LIMG)     // 3136

typedef const float* fp32p;

// ============================================================================
// Generic tiled GEMM:  C = A @ W^T   (+ epilogue)
//   TM=32, TN=64, 256 threads, 2x4 micro-tile.
//   AT: A stored K-major (A[k*lda + m]) -> transpose-free A staging
//   CT: store C transposed (C[n*ldc + m])
//   gridDim.z = K-split; each z writes partial to C + z*M*ldc (CT=0 only).
//   EPI: 0 = plain store, 1 = +bias then softplus
// ============================================================================
template<int BK, int EPI, int AT, int CT>
__global__ __launch_bounds__(256) void gemm_kernel(
    const float* __restrict__ A, int lda,
    const float* __restrict__ W, int K,      // W is N x K row-major
    float* __restrict__ C, int ldc,
    int M, int N,
    const float* __restrict__ bias)
{
    __shared__ __align__(16) float As[BK][36];    // [k][m]
    __shared__ __align__(16) float Ws[BK][68];    // [k][n]
    const int m0 = blockIdx.x * 32;
    const int n0 = blockIdx.y * 64;
    const int tid = threadIdx.x;
    const int tm = (tid & 15) * 2;
    const int tn = (tid >> 4) * 4;
    constexpr int KQ = BK / 4;

    const int kper = K / (int)gridDim.z;
    const int k0s = blockIdx.z * kper;
    if (!CT && gridDim.z > 1) C += (size_t)blockIdx.z * M * ldc;

    float acc[2][4];
    #pragma unroll
    for (int i = 0; i < 2; ++i)
        #pragma unroll
        for (int j = 0; j < 4; ++j) acc[i][j] = 0.f;

    for (int k0 = k0s; k0 < k0s + kper; k0 += BK) {
        __syncthreads();
        if (AT) {
            // A[k][m]: direct float4 copy, no transpose
            for (int f = tid; f < 8 * BK; f += 256) {
                int kk = f >> 3, mq = f & 7;
                int m = m0 + 4 * mq;
                float4 v = make_float4(0.f, 0.f, 0.f, 0.f);
                if (m < M) v = *(const float4*)(A + (size_t)(k0 + kk) * lda + m);
                *(float4*)&As[kk][4 * mq] = v;
            }
        } else {
            // A[m][k]: transpose to [k][m]
            for (int f = tid; f < 8 * BK; f += 256) {
                int m = f / KQ, kq = f % KQ;
                float4 v = make_float4(0.f, 0.f, 0.f, 0.f);
                if (m0 + m < M) v = *(const float4*)(A + (size_t)(m0 + m) * lda + k0 + 4 * kq);
                As[4*kq+0][m] = v.x; As[4*kq+1][m] = v.y;
                As[4*kq+2][m] = v.z; As[4*kq+3][m] = v.w;
            }
        }
        // stage W tile (64 x BK) -> [k][n]
        for (int f = tid; f < 16 * BK; f += 256) {
            int n = f / KQ, kq = f % KQ;
            float4 v = make_float4(0.f, 0.f, 0.f, 0.f);
            if (n0 + n < N) v = *(const float4*)(W + (size_t)(n0 + n) * K + k0 + 4 * kq);
            Ws[4*kq+0][n] = v.x; Ws[4*kq+1][n] = v.y;
            Ws[4*kq+2][n] = v.z; Ws[4*kq+3][n] = v.w;
        }
        __syncthreads();
        #pragma unroll
        for (int kk = 0; kk < BK; ++kk) {
            float2 a = *(const float2*)&As[kk][tm];
            float4 bb = *(const float4*)&Ws[kk][tn];
            float av[2] = {a.x, a.y};
            float bv[4] = {bb.x, bb.y, bb.z, bb.w};
            #pragma unroll
            for (int i = 0; i < 2; ++i)
                #pragma unroll
                for (int j = 0; j < 4; ++j)
                    acc[i][j] = fmaf(av[i], bv[j], acc[i][j]);
        }
    }

    if (CT) {
        int m = m0 + tm;
        #pragma unroll
        for (int j = 0; j < 4; ++j) {
            int n = n0 + tn + j;
            if (n >= N) continue;
            float v0 = acc[0][j], v1 = acc[1][j];
            if (EPI == 1) {
                v0 += bias[n]; v0 = (v0 > 20.f) ? v0 : log1pf(__expf(v0));
                v1 += bias[n]; v1 = (v1 > 20.f) ? v1 : log1pf(__expf(v1));
            }
            if (m + 1 < M) {
                float2 st = make_float2(v0, v1);
                *(float2*)(C + (size_t)n * ldc + m) = st;
            } else if (m < M) {
                C[(size_t)n * ldc + m] = v0;
            }
        }
    } else {
        #pragma unroll
        for (int i = 0; i < 2; ++i) {
            int m = m0 + tm + i;
            if (m >= M) continue;
            #pragma unroll
            for (int j = 0; j < 4; ++j) {
                int n = n0 + tn + j;
                if (n >= N) continue;
                float v = acc[i][j];
                if (EPI == 1) { v += bias[n]; v = (v > 20.f) ? v : log1pf(__expf(v)); }
                C[(size_t)m * ldc + n] = v;
            }
        }
    }
}

// ============================================================================
// img embed GEMM partials: epart[z][b*196+p][d] = sum_{k in split z} img*W
// ============================================================================
__global__ __launch_bounds__(256) void embed_img_kernel(
    fp32p img, fp32p pi_w, float* __restrict__ epart)
{
    __shared__ __align__(16) float As[28][36];   // [k][p]
    __shared__ __align__(16) float Ws[28][68];   // [k][d]
    const int b  = blockIdx.x / 7;
    const int p0 = (blockIdx.x % 7) * 32;
    const int n0 = blockIdx.y * 64;
    const int tid = threadIdx.x;
    const int tm = (tid & 15) * 2;
    const int tn = (tid >> 4) * 4;
    const int k0s = blockIdx.z * 784;

    float acc[2][4];
    #pragma unroll
    for (int i = 0; i < 2; ++i)
        #pragma unroll
        for (int j = 0; j < 4; ++j) acc[i][j] = 0.f;

    const float* imgb = img + (size_t)b * KIMG * LIMG;

    for (int k0 = k0s; k0 < k0s + 784; k0 += 28) {
        __syncthreads();
        for (int f = tid; f < 28 * 8; f += 256) {
            int kk = f >> 3, pq = f & 7;
            int p = p0 + 4 * pq;
            float4 v = make_float4(0.f, 0.f, 0.f, 0.f);
            if (p < LIMG) v = *(const float4*)(imgb + (size_t)(k0 + kk) * LIMG + p);
            *(float4*)&As[kk][4 * pq] = v;
        }
        for (int f = tid; f < 64 * 7; f += 256) {
            int n = f / 7, kq = f % 7;
            float4 v = *(const float4*)(pi_w + (size_t)(n0 + n) * KIMG + k0 + 4 * kq);
            Ws[4*kq+0][n] = v.x; Ws[4*kq+1][n] = v.y;
            Ws[4*kq+2][n] = v.z; Ws[4*kq+3][n] = v.w;
        }
        __syncthreads();
        #pragma unroll
        for (int kk = 0; kk < 28; ++kk) {
            float2 a = *(const float2*)&As[kk][tm];
            float4 bb = *(const float4*)&Ws[kk][tn];
            float av[2] = {a.x, a.y};
            float bv[4] = {bb.x, bb.y, bb.z, bb.w};
            #pragma unroll
            for (int i = 0; i < 2; ++i)
                #pragma unroll
                for (int j = 0; j < 4; ++j)
                    acc[i][j] = fmaf(av[i], bv[j], acc[i][j]);
        }
    }

    float* ep = epart + (size_t)blockIdx.z * N_IMG * D_MODEL;
    #pragma unroll
    for (int i = 0; i < 2; ++i) {
        int p = p0 + tm + i;
        if (p >= LIMG) continue;
        float4 o = make_float4(acc[i][0], acc[i][1], acc[i][2], acc[i][3]);
        *(float4*)(ep + ((size_t)b * LIMG + p) * D_MODEL + n0 + tn) = o;
    }
}

// img finish: seq[b][1+p][d] = ep0 + ep1 + pi_b[d] + PE(1+p, d)
__global__ __launch_bounds__(256) void img_finish_kernel(
    const float* __restrict__ epart, fp32p pi_b, float* __restrict__ seq)
{
    int idx = (blockIdx.x * 256 + threadIdx.x) * 4;
    int d0  = idx & (D_MODEL - 1);
    int row = idx >> 8;
    int b = row / LIMG, p = row % LIMG;
    int l = p + 1;

    float4 a = *(const float4*)(epart + idx);
    float4 c = *(const float4*)(epart + (size_t)N_IMG * D_MODEL + idx);
    float4 bb = *(const float4*)(pi_b + d0);

    const float cpe = -9.210340371976184f / 256.0f;
    float diva = __expf((float)d0 * cpe);
    float divb = __expf((float)(d0 + 2) * cpe);
    float4 o;
    o.x = a.x + c.x + bb.x + sinf((float)l * diva);
    o.y = a.y + c.y + bb.y + cosf((float)l * diva);
    o.z = a.z + c.z + bb.z + sinf((float)l * divb);
    o.w = a.w + c.w + bb.w + cosf((float)l * divb);
    *(float4*)(seq + ((size_t)b * LSEQ + l) * D_MODEL + d0) = o;
}

// out finish: d_out = seq + op0 + op1
__global__ __launch_bounds__(256) void out_finish_kernel(
    const float* __restrict__ seq, const float* __restrict__ opart,
    float* __restrict__ out)
{
    int idx = (blockIdx.x * 256 + threadIdx.x) * 4;
    float4 s = *(const float4*)(seq + idx);
    float4 a = *(const float4*)(opart + idx);
    float4 c = *(const float4*)(opart + (size_t)N_TOK * D_MODEL + idx);
    float4 o;
    o.x = s.x + a.x + c.x; o.y = s.y + a.y + c.y;
    o.z = s.z + a.z + c.z; o.w = s.w + a.w + c.w;
    *(float4*)(out + idx) = o;
}

// small-token embed (text l=0, first l=197, last l=198): 48 blocks
__global__ __launch_bounds__(256) void embed_small_kernel(
    fp32p text, fp32p firsth, fp32p lasth,
    fp32p pt_w, fp32p pt_b, fp32p pf_w, fp32p pf_b, fp32p pl_w, fp32p pl_b,
    float* __restrict__ seq)
{
    __shared__ float in_s[KHID];
    int b = blockIdx.x / 3, c = blockIdx.x % 3;
    int tid = threadIdx.x;

    const float *src, *w, *bias; int K, l;
    if (c == 0)      { src = text   + (size_t)b*KTXT; w = pt_w; bias = pt_b; K = KTXT; l = 0; }
    else if (c == 1) { src = firsth + (size_t)b*KHID; w = pf_w; bias = pf_b; K = KHID; l = LIMG+1; }
    else             { src = lasth  + (size_t)b*KHID; w = pl_w; bias = pl_b; K = KHID; l = LIMG+2; }

    for (int k0 = tid*4; k0 < K; k0 += 256*4)
        *(float4*)&in_s[k0] = *(const float4*)(src + k0);
    __syncthreads();

    int d = tid;
    const float* wr = w + (size_t)d*K;
    float acc = 0.f;
    for (int k = 0; k < K; k += 8) {
        float4 f0 = *(const float4*)(wr + k);
        float4 f1 = *(const float4*)(wr + k + 4);
        acc = fmaf(f0.x, in_s[k+0], acc); acc = fmaf(f0.y, in_s[k+1], acc);
        acc = fmaf(f0.z, in_s[k+2], acc); acc = fmaf(f0.w, in_s[k+3], acc);
        acc = fmaf(f1.x, in_s[k+4], acc); acc = fmaf(f1.y, in_s[k+5], acc);
        acc = fmaf(f1.z, in_s[k+6], acc); acc = fmaf(f1.w, in_s[k+7], acc);
    }
    acc += bias[d];
    const float cpe = -9.210340371976184f / 256.0f;
    float div = __expf((float)(d & ~1) * cpe);
    float ang = (float)l * div;
    acc += (d & 1) ? cosf(ang) : sinf(ang);
    seq[((size_t)b*LSEQ + l)*D_MODEL + d] = acc;
}

// ============================================================================
// causal conv(4) + silu over transposed layout:
//   x = xz_T[d][m] (d<512), out xs_T[d][m], m = b*199+t
// ============================================================================
__global__ __launch_bounds__(256) void conv_t_kernel(
    const float* __restrict__ xz_T, fp32p conv_w, fp32p conv_b,
    float* __restrict__ xs_T)
{
    int m = blockIdx.x * 256 + threadIdx.x;
    if (m >= N_TOK) return;
    int d = blockIdx.y;
    int t = m % LSEQ;
    const float* xr = xz_T + (size_t)d * N_TOK;
    float w0 = conv_w[d*D_CONV + 0], w1 = conv_w[d*D_CONV + 1];
    float w2 = conv_w[d*D_CONV + 2], w3 = conv_w[d*D_CONV + 3];
    float acc = conv_b[d];
    if (t >= 3) {
        acc = fmaf(xr[m-3], w0, acc); acc = fmaf(xr[m-2], w1, acc);
        acc = fmaf(xr[m-1], w2, acc); acc = fmaf(xr[m],   w3, acc);
    } else {
        if (t >= 3) acc = fmaf(xr[m-3], w0, acc);
        if (t >= 2) acc = fmaf(xr[m-2], w1, acc);
        if (t >= 1) acc = fmaf(xr[m-1], w2, acc);
        acc = fmaf(xr[m], w3, acc);
    }
    float sig = 1.f / (1.f + __expf(-acc));
    xs_T[(size_t)d * N_TOK + m] = acc * sig;
}

// ============================================================================
// selective scan, deferred-reduce version.
//   One wave per 2 channels (b, d0=2k, d1=2k+1); lanes 0-31 own d0 (4
//   states/lane), lanes 32-63 own d1. NO per-step shuffle butterfly: each
//   lane writes its scalar partial to LDS; every 32-step chunk the 64 lanes
//   become (channel, t_loc) reduce tasks, sum 32 partials via ds_read_b128,
//   apply x*D + silu(z) gate, and store y coalesced along t.
//   In-wave DS ordering makes this barrier-free.
// ============================================================================
#define TCH 32
__global__ __launch_bounds__(256) void scan_kernel(
    const float* __restrict__ delta_T, const float* __restrict__ xs_T,
    const float* __restrict__ xz_T, const float* __restrict__ dbc_ws,
    fp32p A_log, fp32p Dp, float* __restrict__ y_T)
{
    __shared__ __align__(16) float part[4][TCH][68];  // [wave][t_loc][lane]
    const int wv   = threadIdx.x >> 6;
    const int wid  = blockIdx.x*4 + wv;               // 4096 waves
    const int lane = threadIdx.x & 63;
    const int b  = wid >> 8;
    const int dp = wid & 255;
    const int sl = lane & 31;
    const int ch = lane >> 5;
    const int d  = dp*2 + ch;

    float4 Av = *(const float4*)(A_log + (size_t)d*D_STATE + 4*sl);
    const float A0 = -__expf(Av.x), A1 = -__expf(Av.y);
    const float A2 = -__expf(Av.z), A3 = -__expf(Av.w);

    const float* dl  = delta_T + (size_t)d*N_TOK + b*LSEQ;
    const float* xl  = xs_T    + (size_t)d*N_TOK + b*LSEQ;
    const float* dbc = dbc_ws  + (size_t)b*LSEQ*272;
    float* pw = &part[wv][0][0];

    // reduce-task view: this lane reduces channel rc at t_loc = sl
    const int rd = dp*2 + ch;           // same split: ch doubles as rc
    const float Dr = Dp[rd];
    const float* xr = xs_T + (size_t)rd*N_TOK + b*LSEQ;
    const float* zr = xz_T + (size_t)(D_INNER + rd)*N_TOK + b*LSEQ;
    float*       yr = y_T  + (size_t)rd*N_TOK + b*LSEQ;

    float h0 = 0.f, h1 = 0.f, h2 = 0.f, h3 = 0.f;

    for (int t0 = 0; t0 < LSEQ; t0 += TCH) {
        const int tc = (LSEQ - t0 < TCH) ? (LSEQ - t0) : TCH;
        for (int tt = 0; tt < tc; ++tt) {
            const int t = t0 + tt;
            const float* row = dbc + (size_t)t*272;
            float da = dl[t];
            float xa = xl[t];
            float4 Ba = *(const float4*)(row + DT_RANK + 4*sl);
            float4 Ca = *(const float4*)(row + DT_RANK + D_STATE + 4*sl);
            float du = da * xa;
            h0 = fmaf(__expf(da*A0), h0, du*Ba.x);
            h1 = fmaf(__expf(da*A1), h1, du*Ba.y);
            h2 = fmaf(__expf(da*A2), h2, du*Ba.z);
            h3 = fmaf(__expf(da*A3), h3, du*Ba.w);
            float p = fmaf(h0, Ca.x, fmaf(h1, Ca.y, fmaf(h2, Ca.z, h3*Ca.w)));
            pw[tt*68 + lane] = p;
        }
        // chunk reduce: lane -> (rc=ch, t_loc=sl); in-wave DS ops are in-order
        if (sl < tc) {
            const float* pr = pw + sl*68 + ch*32;
            float s0 = 0.f, s1 = 0.f;
            #pragma unroll
            for (int k = 0; k < 32; k += 8) {
                float4 v0 = *(const float4*)(pr + k);
                float4 v1 = *(const float4*)(pr + k + 4);
                s0 += (v0.x + v0.y) + (v0.z + v0.w);
                s1 += (v1.x + v1.y) + (v1.z + v1.w);
            }
            float sum = s0 + s1;
            const int t = t0 + sl;
            float xv = xr[t], zv = zr[t];
            float y = fmaf(xv, Dr, sum);
            yr[t] = y * (zv / (1.f + __expf(-zv)));
        }
    }
}

extern "C" void kernel_launch(void* const* d_in, const int* in_sizes, int n_in,
                              void* d_out, int out_size, void* d_ws, size_t ws_size,
                              hipStream_t stream)
{
    fp32p text   = (fp32p)d_in[0];
    fp32p img    = (fp32p)d_in[1];
    fp32p firsth = (fp32p)d_in[2];
    fp32p lasth  = (fp32p)d_in[3];
    fp32p pt_w   = (fp32p)d_in[4];
    fp32p pt_b   = (fp32p)d_in[5];
    fp32p pi_w   = (fp32p)d_in[6];
    fp32p pi_b   = (fp32p)d_in[7];
    fp32p pf_w   = (fp32p)d_in[8];
    fp32p pf_b   = (fp32p)d_in[9];
    fp32p pl_w   = (fp32p)d_in[10];
    fp32p pl_b   = (fp32p)d_in[11];
    fp32p inp_w  = (fp32p)d_in[12];
    fp32p conv_w = (fp32p)d_in[13];
    fp32p conv_b = (fp32p)d_in[14];
    fp32p xp_w   = (fp32p)d_in[15];
    fp32p dt_w   = (fp32p)d_in[16];
    fp32p dt_b   = (fp32p)d_in[17];
    fp32p A_log  = (fp32p)d_in[18];
    fp32p Dp     = (fp32p)d_in[19];
    fp32p out_w  = (fp32p)d_in[20];

    float* ws      = (float*)d_ws;
    float* seq     = ws;                                   // 3184*256
    float* xz_T    = seq     + (size_t)N_TOK*D_MODEL;      // 1024*3184 (+pad)
    float* xs_T    = xz_T    + (size_t)1024*N_TOK + 16;    // 512*3184 (+pad)
    float* dbc_ws  = xs_T    + (size_t)D_INNER*N_TOK + 16; // 3184*272
    float* delta_T = dbc_ws  + (size_t)N_TOK*272;          // 512*3184 (+pad)
    float* y_T     = delta_T + (size_t)D_INNER*N_TOK + 16; // 512*3184 (+pad)
    float* epart   = y_T     + (size_t)D_INNER*N_TOK + 16; // 2*3136*256
    float* opart   = epart   + (size_t)2*N_IMG*D_MODEL;    // 2*3184*256

    // 1. embeddings
    embed_small_kernel<<<BATCH*3, 256, 0, stream>>>(
        text, firsth, lasth, pt_w, pt_b, pf_w, pf_b, pl_w, pl_b, seq);
    embed_img_kernel<<<dim3(BATCH*7, 4, 2), 256, 0, stream>>>(img, pi_w, epart);
    img_finish_kernel<<<N_IMG*D_MODEL/1024, 256, 0, stream>>>(epart, pi_b, seq);

    // 2. in_proj: (3184 x 256) @ (1024 x 256)^T -> xz_T [1024][3184]
    gemm_kernel<32, 0, 0, 1><<<dim3(100, 16), 256, 0, stream>>>(
        seq, D_MODEL, inp_w, D_MODEL, xz_T, N_TOK, N_TOK, 1024, nullptr);

    // 3. conv + silu over [d][m]
    conv_t_kernel<<<dim3(13, D_INNER), 256, 0, stream>>>(xz_T, conv_w, conv_b, xs_T);

    // 4. x_proj: A = xs_T (K-major), -> dbc token-major [m][272]
    gemm_kernel<32, 0, 1, 0><<<dim3(100, 5), 256, 0, stream>>>(
        xs_T, N_TOK, xp_w, D_INNER, dbc_ws, 272, N_TOK, 272, nullptr);

    // 5. dt_proj + softplus: -> delta_T [512][3184]
    gemm_kernel<16, 1, 0, 1><<<dim3(100, 8), 256, 0, stream>>>(
        dbc_ws, 272, dt_w, DT_RANK, delta_T, N_TOK, N_TOK, D_INNER, dt_b);

    // 6. scan (4096 waves, 2 channels/wave), deferred LDS reduce
    scan_kernel<<<BATCH*D_INNER/8, 256, 0, stream>>>(
        delta_T, xs_T, xz_T, dbc_ws, A_log, Dp, y_T);

    // 7. out_proj: A = y_T (K-major), K-split 2 -> partials; finish adds resid
    gemm_kernel<32, 0, 1, 0><<<dim3(100, 4, 2), 256, 0, stream>>>(
        y_T, N_TOK, out_w, D_INNER, opart, D_MODEL, N_TOK, D_MODEL, nullptr);
    out_finish_kernel<<<N_TOK*D_MODEL/1024, 256, 0, stream>>>(seq, opart, (float*)d_out);
}

// Round 9
// 394.279 us; speedup vs baseline: 4.3738x; 1.2169x over previous
//
#include <hip/hip_runtime.h>
#include <hip/hip_bf16.h>
#include <math.h>

#define D_MODEL 256
#define D_STATE 128
#define D_CONV  4
#define D_INNER 512
#define DT_RANK 16
#define BATCH   16
#define LIMG    196
#define LSEQ    199
#define KTXT    768
#define KIMG    1568
#define KHID    3584
#define N_TOK   (BATCH*LSEQ)     // 3184
#define N_IMG   (BATCH*LIMG)     // 3136

typedef const float* fp32p;

// ============================================================================
// Generic tiled GEMM:  C = A @ W^T   (+ epilogue)
//   TM=32, TN=64, 256 threads, 2x4 micro-tile.
//   AT: A stored K-major; CT: store C transposed; gridDim.z = K-split.
//   EPI: 0 = plain store, 1 = +bias then softplus
// ============================================================================
template<int BK, int EPI, int AT, int CT>
__global__ __launch_bounds__(256) void gemm_kernel(
    const float* __restrict__ A, int lda,
    const float* __restrict__ W, int K,      // W is N x K row-major
    float* __restrict__ C, int ldc,
    int M, int N,
    const float* __restrict__ bias)
{
    __shared__ __align__(16) float As[BK][36];    // [k][m]
    __shared__ __align__(16) float Ws[BK][68];    // [k][n]
    const int m0 = blockIdx.x * 32;
    const int n0 = blockIdx.y * 64;
    const int tid = threadIdx.x;
    const int tm = (tid & 15) * 2;
    const int tn = (tid >> 4) * 4;
    constexpr int KQ = BK / 4;

    const int kper = K / (int)gridDim.z;
    const int k0s = blockIdx.z * kper;
    if (!CT && gridDim.z > 1) C += (size_t)blockIdx.z * M * ldc;

    float acc[2][4];
    #pragma unroll
    for (int i = 0; i < 2; ++i)
        #pragma unroll
        for (int j = 0; j < 4; ++j) acc[i][j] = 0.f;

    for (int k0 = k0s; k0 < k0s + kper; k0 += BK) {
        __syncthreads();
        if (AT) {
            for (int f = tid; f < 8 * BK; f += 256) {
                int kk = f >> 3, mq = f & 7;
                int m = m0 + 4 * mq;
                float4 v = make_float4(0.f, 0.f, 0.f, 0.f);
                if (m < M) v = *(const float4*)(A + (size_t)(k0 + kk) * lda + m);
                *(float4*)&As[kk][4 * mq] = v;
            }
        } else {
            for (int f = tid; f < 8 * BK; f += 256) {
                int m = f / KQ, kq = f % KQ;
                float4 v = make_float4(0.f, 0.f, 0.f, 0.f);
                if (m0 + m < M) v = *(const float4*)(A + (size_t)(m0 + m) * lda + k0 + 4 * kq);
                As[4*kq+0][m] = v.x; As[4*kq+1][m] = v.y;
                As[4*kq+2][m] = v.z; As[4*kq+3][m] = v.w;
            }
        }
        for (int f = tid; f < 16 * BK; f += 256) {
            int n = f / KQ, kq = f % KQ;
            float4 v = make_float4(0.f, 0.f, 0.f, 0.f);
            if (n0 + n < N) v = *(const float4*)(W + (size_t)(n0 + n) * K + k0 + 4 * kq);
            Ws[4*kq+0][n] = v.x; Ws[4*kq+1][n] = v.y;
            Ws[4*kq+2][n] = v.z; Ws[4*kq+3][n] = v.w;
        }
        __syncthreads();
        #pragma unroll
        for (int kk = 0; kk < BK; ++kk) {
            float2 a = *(const float2*)&As[kk][tm];
            float4 bb = *(const float4*)&Ws[kk][tn];
            float av[2] = {a.x, a.y};
            float bv[4] = {bb.x, bb.y, bb.z, bb.w};
            #pragma unroll
            for (int i = 0; i < 2; ++i)
                #pragma unroll
                for (int j = 0; j < 4; ++j)
                    acc[i][j] = fmaf(av[i], bv[j], acc[i][j]);
        }
    }

    if (CT) {
        int m = m0 + tm;
        #pragma unroll
        for (int j = 0; j < 4; ++j) {
            int n = n0 + tn + j;
            if (n >= N) continue;
            float v0 = acc[0][j], v1 = acc[1][j];
            if (EPI == 1) {
                v0 += bias[n]; v0 = (v0 > 20.f) ? v0 : log1pf(__expf(v0));
                v1 += bias[n]; v1 = (v1 > 20.f) ? v1 : log1pf(__expf(v1));
            }
            if (m + 1 < M) {
                float2 st = make_float2(v0, v1);
                *(float2*)(C + (size_t)n * ldc + m) = st;
            } else if (m < M) {
                C[(size_t)n * ldc + m] = v0;
            }
        }
    } else {
        #pragma unroll
        for (int i = 0; i < 2; ++i) {
            int m = m0 + tm + i;
            if (m >= M) continue;
            #pragma unroll
            for (int j = 0; j < 4; ++j) {
                int n = n0 + tn + j;
                if (n >= N) continue;
                float v = acc[i][j];
                if (EPI == 1) { v += bias[n]; v = (v > 20.f) ? v : log1pf(__expf(v)); }
                C[(size_t)m * ldc + n] = v;
            }
        }
    }
}

// ============================================================================
// img embed GEMM partials: epart[z][b*196+p][d] = sum_{k in split z} img*W
// ============================================================================
__global__ __launch_bounds__(256) void embed_img_kernel(
    fp32p img, fp32p pi_w, float* __restrict__ epart)
{
    __shared__ __align__(16) float As[28][36];   // [k][p]
    __shared__ __align__(16) float Ws[28][68];   // [k][d]
    const int b  = blockIdx.x / 7;
    const int p0 = (blockIdx.x % 7) * 32;
    const int n0 = blockIdx.y * 64;
    const int tid = threadIdx.x;
    const int tm = (tid & 15) * 2;
    const int tn = (tid >> 4) * 4;
    const int k0s = blockIdx.z * 784;

    float acc[2][4];
    #pragma unroll
    for (int i = 0; i < 2; ++i)
        #pragma unroll
        for (int j = 0; j < 4; ++j) acc[i][j] = 0.f;

    const float* imgb = img + (size_t)b * KIMG * LIMG;

    for (int k0 = k0s; k0 < k0s + 784; k0 += 28) {
        __syncthreads();
        for (int f = tid; f < 28 * 8; f += 256) {
            int kk = f >> 3, pq = f & 7;
            int p = p0 + 4 * pq;
            float4 v = make_float4(0.f, 0.f, 0.f, 0.f);
            if (p < LIMG) v = *(const float4*)(imgb + (size_t)(k0 + kk) * LIMG + p);
            *(float4*)&As[kk][4 * pq] = v;
        }
        for (int f = tid; f < 64 * 7; f += 256) {
            int n = f / 7, kq = f % 7;
            float4 v = *(const float4*)(pi_w + (size_t)(n0 + n) * KIMG + k0 + 4 * kq);
            Ws[4*kq+0][n] = v.x; Ws[4*kq+1][n] = v.y;
            Ws[4*kq+2][n] = v.z; Ws[4*kq+3][n] = v.w;
        }
        __syncthreads();
        #pragma unroll
        for (int kk = 0; kk < 28; ++kk) {
            float2 a = *(const float2*)&As[kk][tm];
            float4 bb = *(const float4*)&Ws[kk][tn];
            float av[2] = {a.x, a.y};
            float bv[4] = {bb.x, bb.y, bb.z, bb.w};
            #pragma unroll
            for (int i = 0; i < 2; ++i)
                #pragma unroll
                for (int j = 0; j < 4; ++j)
                    acc[i][j] = fmaf(av[i], bv[j], acc[i][j]);
        }
    }

    float* ep = epart + (size_t)blockIdx.z * N_IMG * D_MODEL;
    #pragma unroll
    for (int i = 0; i < 2; ++i) {
        int p = p0 + tm + i;
        if (p >= LIMG) continue;
        float4 o = make_float4(acc[i][0], acc[i][1], acc[i][2], acc[i][3]);
        *(float4*)(ep + ((size_t)b * LIMG + p) * D_MODEL + n0 + tn) = o;
    }
}

// img finish: seq[b][1+p][d] = ep0 + ep1 + pi_b[d] + PE(1+p, d)
__global__ __launch_bounds__(256) void img_finish_kernel(
    const float* __restrict__ epart, fp32p pi_b, float* __restrict__ seq)
{
    int idx = (blockIdx.x * 256 + threadIdx.x) * 4;
    int d0  = idx & (D_MODEL - 1);
    int row = idx >> 8;
    int b = row / LIMG, p = row % LIMG;
    int l = p + 1;

    float4 a = *(const float4*)(epart + idx);
    float4 c = *(const float4*)(epart + (size_t)N_IMG * D_MODEL + idx);
    float4 bb = *(const float4*)(pi_b + d0);

    const float cpe = -9.210340371976184f / 256.0f;
    float diva = __expf((float)d0 * cpe);
    float divb = __expf((float)(d0 + 2) * cpe);
    float4 o;
    o.x = a.x + c.x + bb.x + sinf((float)l * diva);
    o.y = a.y + c.y + bb.y + cosf((float)l * diva);
    o.z = a.z + c.z + bb.z + sinf((float)l * divb);
    o.w = a.w + c.w + bb.w + cosf((float)l * divb);
    *(float4*)(seq + ((size_t)b * LSEQ + l) * D_MODEL + d0) = o;
}

// out finish: d_out = seq + op0 + op1
__global__ __launch_bounds__(256) void out_finish_kernel(
    const float* __restrict__ seq, const float* __restrict__ opart,
    float* __restrict__ out)
{
    int idx = (blockIdx.x * 256 + threadIdx.x) * 4;
    float4 s = *(const float4*)(seq + idx);
    float4 a = *(const float4*)(opart + idx);
    float4 c = *(const float4*)(opart + (size_t)N_TOK * D_MODEL + idx);
    float4 o;
    o.x = s.x + a.x + c.x; o.y = s.y + a.y + c.y;
    o.z = s.z + a.z + c.z; o.w = s.w + a.w + c.w;
    *(float4*)(out + idx) = o;
}

// ============================================================================
// text/first/last embed as chunked partial-GEMM.
//   31 k-chunks of 256: text(K=768)->3, first(K=3584)->14, last->14.
//   grid (31, 4): each block computes a 16x64 partial -> ppart[chunk][16][256]
// ============================================================================
#define KCH 256
__global__ __launch_bounds__(256) void embed3_kernel(
    fp32p text, fp32p firsth, fp32p lasth,
    fp32p pt_w, fp32p pf_w, fp32p pl_w,
    float* __restrict__ ppart)
{
    __shared__ __align__(16) float As[32][20];   // [k][m], 16 tokens
    __shared__ __align__(16) float Ws[32][68];   // [k][n]
    const int chunk = blockIdx.x;
    const int n0 = blockIdx.y * 64;
    const float *src, *w; int k0, K;
    if (chunk < 3)       { src = text;   w = pt_w; k0 = chunk*KCH;      K = KTXT; }
    else if (chunk < 17) { src = firsth; w = pf_w; k0 = (chunk-3)*KCH;  K = KHID; }
    else                 { src = lasth;  w = pl_w; k0 = (chunk-17)*KCH; K = KHID; }

    const int tid = threadIdx.x;
    const int tm = (tid & 7) * 2;
    const int tn = (tid >> 3) * 2;
    float acc[2][2] = {{0.f,0.f},{0.f,0.f}};

    for (int ks = 0; ks < KCH; ks += 32) {
        __syncthreads();
        // A: 16 b x 32 k -> As[k][m]
        if (tid < 128) {
            int m = tid >> 3, kq = tid & 7;
            float4 v = *(const float4*)(src + (size_t)m*K + k0 + ks + 4*kq);
            As[4*kq+0][m]=v.x; As[4*kq+1][m]=v.y; As[4*kq+2][m]=v.z; As[4*kq+3][m]=v.w;
        }
        // W: 64 n x 32 k -> Ws[k][n]
        for (int f = tid; f < 512; f += 256) {
            int n = f >> 3, kq = f & 7;
            float4 v = *(const float4*)(w + (size_t)(n0+n)*K + k0 + ks + 4*kq);
            Ws[4*kq+0][n]=v.x; Ws[4*kq+1][n]=v.y; Ws[4*kq+2][n]=v.z; Ws[4*kq+3][n]=v.w;
        }
        __syncthreads();
        #pragma unroll
        for (int kk = 0; kk < 32; ++kk) {
            float2 a = *(const float2*)&As[kk][tm];
            float2 b = *(const float2*)&Ws[kk][tn];
            acc[0][0] = fmaf(a.x, b.x, acc[0][0]);
            acc[0][1] = fmaf(a.x, b.y, acc[0][1]);
            acc[1][0] = fmaf(a.y, b.x, acc[1][0]);
            acc[1][1] = fmaf(a.y, b.y, acc[1][1]);
        }
    }
    float* pp = ppart + (size_t)chunk*16*256;
    pp[(size_t)(tm+0)*256 + n0+tn+0] = acc[0][0];
    pp[(size_t)(tm+0)*256 + n0+tn+1] = acc[0][1];
    pp[(size_t)(tm+1)*256 + n0+tn+0] = acc[1][0];
    pp[(size_t)(tm+1)*256 + n0+tn+1] = acc[1][1];
}

// finish: seq[b][l_c][d] = sum_chunks + bias_c[d] + PE(l_c, d);  48 blocks
__global__ __launch_bounds__(256) void embed3_finish_kernel(
    const float* __restrict__ ppart, fp32p pt_b, fp32p pf_b, fp32p pl_b,
    float* __restrict__ seq)
{
    int idx = blockIdx.x*256 + threadIdx.x;   // [0, 48*256)
    int d = idx & 255;
    int bc = idx >> 8;
    int b = bc / 3, c = bc % 3;
    int c0, nch, l; const float* bias;
    if (c == 0)      { c0 = 0;  nch = 3;  l = 0;        bias = pt_b; }
    else if (c == 1) { c0 = 3;  nch = 14; l = LIMG+1;   bias = pf_b; }
    else             { c0 = 17; nch = 14; l = LIMG+2;   bias = pl_b; }
    float s = bias[d];
    for (int ch = 0; ch < nch; ++ch)
        s += ppart[(size_t)(c0+ch)*16*256 + (size_t)b*256 + d];
    const float cpe = -9.210340371976184f / 256.0f;
    float div = __expf((float)(d & ~1) * cpe);
    float ang = (float)l * div;
    s += (d & 1) ? cosf(ang) : sinf(ang);
    seq[((size_t)b*LSEQ + l)*D_MODEL + d] = s;
}

// ============================================================================
// causal conv(4) + silu over transposed layout
// ============================================================================
__global__ __launch_bounds__(256) void conv_t_kernel(
    const float* __restrict__ xz_T, fp32p conv_w, fp32p conv_b,
    float* __restrict__ xs_T)
{
    int m = blockIdx.x * 256 + threadIdx.x;
    if (m >= N_TOK) return;
    int d = blockIdx.y;
    int t = m % LSEQ;
    const float* xr = xz_T + (size_t)d * N_TOK;
    float w0 = conv_w[d*D_CONV + 0], w1 = conv_w[d*D_CONV + 1];
    float w2 = conv_w[d*D_CONV + 2], w3 = conv_w[d*D_CONV + 3];
    float acc = conv_b[d];
    if (t >= 3) {
        acc = fmaf(xr[m-3], w0, acc); acc = fmaf(xr[m-2], w1, acc);
        acc = fmaf(xr[m-1], w2, acc); acc = fmaf(xr[m],   w3, acc);
    } else {
        if (t >= 2) acc = fmaf(xr[m-2], w1, acc);
        if (t >= 1) acc = fmaf(xr[m-1], w2, acc);
        acc = fmaf(xr[m], w3, acc);
    }
    float sig = 1.f / (1.f + __expf(-acc));
    xs_T[(size_t)d * N_TOK + m] = acc * sig;
}

// ============================================================================
// selective scan, deferred-reduce version (round-8 design, unchanged)
// ============================================================================
#define TCH 32
__global__ __launch_bounds__(256) void scan_kernel(
    const float* __restrict__ delta_T, const float* __restrict__ xs_T,
    const float* __restrict__ xz_T, const float* __restrict__ dbc_ws,
    fp32p A_log, fp32p Dp, float* __restrict__ y_T)
{
    __shared__ __align__(16) float part[4][TCH][68];  // [wave][t_loc][lane]
    const int wv   = threadIdx.x >> 6;
    const int wid  = blockIdx.x*4 + wv;               // 4096 waves
    const int lane = threadIdx.x & 63;
    const int b  = wid >> 8;
    const int dp = wid & 255;
    const int sl = lane & 31;
    const int ch = lane >> 5;
    const int d  = dp*2 + ch;

    float4 Av = *(const float4*)(A_log + (size_t)d*D_STATE + 4*sl);
    const float A0 = -__expf(Av.x), A1 = -__expf(Av.y);
    const float A2 = -__expf(Av.z), A3 = -__expf(Av.w);

    const float* dl  = delta_T + (size_t)d*N_TOK + b*LSEQ;
    const float* xl  = xs_T    + (size_t)d*N_TOK + b*LSEQ;
    const float* dbc = dbc_ws  + (size_t)b*LSEQ*272;
    float* pw = &part[wv][0][0];

    const int rd = dp*2 + ch;
    const float Dr = Dp[rd];
    const float* xr = xs_T + (size_t)rd*N_TOK + b*LSEQ;
    const float* zr = xz_T + (size_t)(D_INNER + rd)*N_TOK + b*LSEQ;
    float*       yr = y_T  + (size_t)rd*N_TOK + b*LSEQ;

    float h0 = 0.f, h1 = 0.f, h2 = 0.f, h3 = 0.f;

    for (int t0 = 0; t0 < LSEQ; t0 += TCH) {
        const int tc = (LSEQ - t0 < TCH) ? (LSEQ - t0) : TCH;
        for (int tt = 0; tt < tc; ++tt) {
            const int t = t0 + tt;
            const float* row = dbc + (size_t)t*272;
            float da = dl[t];
            float xa = xl[t];
            float4 Ba = *(const float4*)(row + DT_RANK + 4*sl);
            float4 Ca = *(const float4*)(row + DT_RANK + D_STATE + 4*sl);
            float du = da * xa;
            h0 = fmaf(__expf(da*A0), h0, du*Ba.x);
            h1 = fmaf(__expf(da*A1), h1, du*Ba.y);
            h2 = fmaf(__expf(da*A2), h2, du*Ba.z);
            h3 = fmaf(__expf(da*A3), h3, du*Ba.w);
            float p = fmaf(h0, Ca.x, fmaf(h1, Ca.y, fmaf(h2, Ca.z, h3*Ca.w)));
            pw[tt*68 + lane] = p;
        }
        if (sl < tc) {
            const float* pr = pw + sl*68 + ch*32;
            float s0 = 0.f, s1 = 0.f;
            #pragma unroll
            for (int k = 0; k < 32; k += 8) {
                float4 v0 = *(const float4*)(pr + k);
                float4 v1 = *(const float4*)(pr + k + 4);
                s0 += (v0.x + v0.y) + (v0.z + v0.w);
                s1 += (v1.x + v1.y) + (v1.z + v1.w);
            }
            float sum = s0 + s1;
            const int t = t0 + sl;
            float xv = xr[t], zv = zr[t];
            float y = fmaf(xv, Dr, sum);
            yr[t] = y * (zv / (1.f + __expf(-zv)));
        }
    }
}

extern "C" void kernel_launch(void* const* d_in, const int* in_sizes, int n_in,
                              void* d_out, int out_size, void* d_ws, size_t ws_size,
                              hipStream_t stream)
{
    fp32p text   = (fp32p)d_in[0];
    fp32p img    = (fp32p)d_in[1];
    fp32p firsth = (fp32p)d_in[2];
    fp32p lasth  = (fp32p)d_in[3];
    fp32p pt_w   = (fp32p)d_in[4];
    fp32p pt_b   = (fp32p)d_in[5];
    fp32p pi_w   = (fp32p)d_in[6];
    fp32p pi_b   = (fp32p)d_in[7];
    fp32p pf_w   = (fp32p)d_in[8];
    fp32p pf_b   = (fp32p)d_in[9];
    fp32p pl_w   = (fp32p)d_in[10];
    fp32p pl_b   = (fp32p)d_in[11];
    fp32p inp_w  = (fp32p)d_in[12];
    fp32p conv_w = (fp32p)d_in[13];
    fp32p conv_b = (fp32p)d_in[14];
    fp32p xp_w   = (fp32p)d_in[15];
    fp32p dt_w   = (fp32p)d_in[16];
    fp32p dt_b   = (fp32p)d_in[17];
    fp32p A_log  = (fp32p)d_in[18];
    fp32p Dp     = (fp32p)d_in[19];
    fp32p out_w  = (fp32p)d_in[20];

    float* ws      = (float*)d_ws;
    float* seq     = ws;                                   // 3184*256
    float* xz_T    = seq     + (size_t)N_TOK*D_MODEL;      // 1024*3184 (+pad)
    float* xs_T    = xz_T    + (size_t)1024*N_TOK + 16;    // 512*3184 (+pad)
    float* dbc_ws  = xs_T    + (size_t)D_INNER*N_TOK + 16; // 3184*272
    float* delta_T = dbc_ws  + (size_t)N_TOK*272;          // 512*3184 (+pad)
    float* y_T     = delta_T + (size_t)D_INNER*N_TOK + 16; // 512*3184 (+pad)
    float* epart   = y_T     + (size_t)D_INNER*N_TOK + 16; // 2*3136*256
    float* opart   = epart   + (size_t)2*N_IMG*D_MODEL;    // 2*3184*256
    float* ppart   = opart   + (size_t)2*N_TOK*D_MODEL;    // 31*16*256

    // 1. embeddings
    embed3_kernel<<<dim3(31, 4), 256, 0, stream>>>(
        text, firsth, lasth, pt_w, pf_w, pl_w, ppart);
    embed3_finish_kernel<<<48, 256, 0, stream>>>(ppart, pt_b, pf_b, pl_b, seq);
    embed_img_kernel<<<dim3(BATCH*7, 4, 2), 256, 0, stream>>>(img, pi_w, epart);
    img_finish_kernel<<<N_IMG*D_MODEL/1024, 256, 0, stream>>>(epart, pi_b, seq);

    // 2. in_proj: (3184 x 256) @ (1024 x 256)^T -> xz_T [1024][3184]
    gemm_kernel<32, 0, 0, 1><<<dim3(100, 16), 256, 0, stream>>>(
        seq, D_MODEL, inp_w, D_MODEL, xz_T, N_TOK, N_TOK, 1024, nullptr);

    // 3. conv + silu over [d][m]
    conv_t_kernel<<<dim3(13, D_INNER), 256, 0, stream>>>(xz_T, conv_w, conv_b, xs_T);

    // 4. x_proj: A = xs_T (K-major), -> dbc token-major [m][272]
    gemm_kernel<32, 0, 1, 0><<<dim3(100, 5), 256, 0, stream>>>(
        xs_T, N_TOK, xp_w, D_INNER, dbc_ws, 272, N_TOK, 272, nullptr);

    // 5. dt_proj + softplus: -> delta_T [512][3184]
    gemm_kernel<16, 1, 0, 1><<<dim3(100, 8), 256, 0, stream>>>(
        dbc_ws, 272, dt_w, DT_RANK, delta_T, N_TOK, N_TOK, D_INNER, dt_b);

    // 6. scan (4096 waves, 2 channels/wave), deferred LDS reduce
    scan_kernel<<<BATCH*D_INNER/8, 256, 0, stream>>>(
        delta_T, xs_T, xz_T, dbc_ws, A_log, Dp, y_T);

    // 7. out_proj: A = y_T (K-major), K-split 2 -> partials; finish adds resid
    gemm_kernel<32, 0, 1, 0><<<dim3(100, 4, 2), 256, 0, stream>>>(
        y_T, N_TOK, out_w, D_INNER, opart, D_MODEL, N_TOK, D_MODEL, nullptr);
    out_finish_kernel<<<N_TOK*D_MODEL/1024, 256, 0, stream>>>(seq, opart, (float*)d_out);
}

// Round 10
// 381.157 us; speedup vs baseline: 4.5244x; 1.0344x over previous
//
#include <hip/hip_runtime.h>
#include <hip/hip_bf16.h>
#include <math.h>

#define D_MODEL 256
#define D_STATE 128
#define D_CONV  4
#define D_INNER 512
#define DT_RANK 16
#define BATCH   16
#define LIMG    196
#define LSEQ    199
#define KTXT    768
#define KIMG    1568
#define KHID    3584
#define N_TOK   (BATCH*LSEQ)     // 3184
#define N_IMG   (BATCH*LIMG)     // 3136

typedef const float* fp32p;

// ============================================================================
// Generic tiled GEMM:  C = A @ W^T   (+ epilogue)
//   TM=32, TN=64, 256 threads, 2x4 micro-tile.
//   AT: A stored K-major; CT: store C transposed; gridDim.z = K-split.
//   EPI: 0 = plain store, 1 = +bias then softplus
// ============================================================================
template<int BK, int EPI, int AT, int CT>
__global__ __launch_bounds__(256) void gemm_kernel(
    const float* __restrict__ A, int lda,
    const float* __restrict__ W, int K,      // W is N x K row-major
    float* __restrict__ C, int ldc,
    int M, int N,
    const float* __restrict__ bias)
{
    __shared__ __align__(16) float As[BK][36];    // [k][m]
    __shared__ __align__(16) float Ws[BK][68];    // [k][n]
    const int m0 = blockIdx.x * 32;
    const int n0 = blockIdx.y * 64;
    const int tid = threadIdx.x;
    const int tm = (tid & 15) * 2;
    const int tn = (tid >> 4) * 4;
    constexpr int KQ = BK / 4;

    const int kper = K / (int)gridDim.z;
    const int k0s = blockIdx.z * kper;
    if (!CT && gridDim.z > 1) C += (size_t)blockIdx.z * M * ldc;

    float acc[2][4];
    #pragma unroll
    for (int i = 0; i < 2; ++i)
        #pragma unroll
        for (int j = 0; j < 4; ++j) acc[i][j] = 0.f;

    for (int k0 = k0s; k0 < k0s + kper; k0 += BK) {
        __syncthreads();
        if (AT) {
            for (int f = tid; f < 8 * BK; f += 256) {
                int kk = f >> 3, mq = f & 7;
                int m = m0 + 4 * mq;
                float4 v = make_float4(0.f, 0.f, 0.f, 0.f);
                if (m < M) v = *(const float4*)(A + (size_t)(k0 + kk) * lda + m);
                *(float4*)&As[kk][4 * mq] = v;
            }
        } else {
            for (int f = tid; f < 8 * BK; f += 256) {
                int m = f / KQ, kq = f % KQ;
                float4 v = make_float4(0.f, 0.f, 0.f, 0.f);
                if (m0 + m < M) v = *(const float4*)(A + (size_t)(m0 + m) * lda + k0 + 4 * kq);
                As[4*kq+0][m] = v.x; As[4*kq+1][m] = v.y;
                As[4*kq+2][m] = v.z; As[4*kq+3][m] = v.w;
            }
        }
        for (int f = tid; f < 16 * BK; f += 256) {
            int n = f / KQ, kq = f % KQ;
            float4 v = make_float4(0.f, 0.f, 0.f, 0.f);
            if (n0 + n < N) v = *(const float4*)(W + (size_t)(n0 + n) * K + k0 + 4 * kq);
            Ws[4*kq+0][n] = v.x; Ws[4*kq+1][n] = v.y;
            Ws[4*kq+2][n] = v.z; Ws[4*kq+3][n] = v.w;
        }
        __syncthreads();
        #pragma unroll
        for (int kk = 0; kk < BK; ++kk) {
            float2 a = *(const float2*)&As[kk][tm];
            float4 bb = *(const float4*)&Ws[kk][tn];
            float av[2] = {a.x, a.y};
            float bv[4] = {bb.x, bb.y, bb.z, bb.w};
            #pragma unroll
            for (int i = 0; i < 2; ++i)
                #pragma unroll
                for (int j = 0; j < 4; ++j)
                    acc[i][j] = fmaf(av[i], bv[j], acc[i][j]);
        }
    }

    if (CT) {
        int m = m0 + tm;
        #pragma unroll
        for (int j = 0; j < 4; ++j) {
            int n = n0 + tn + j;
            if (n >= N) continue;
            float v0 = acc[0][j], v1 = acc[1][j];
            if (EPI == 1) {
                v0 += bias[n]; v0 = (v0 > 20.f) ? v0 : log1pf(__expf(v0));
                v1 += bias[n]; v1 = (v1 > 20.f) ? v1 : log1pf(__expf(v1));
            }
            if (m + 1 < M) {
                float2 st = make_float2(v0, v1);
                *(float2*)(C + (size_t)n * ldc + m) = st;
            } else if (m < M) {
                C[(size_t)n * ldc + m] = v0;
            }
        }
    } else {
        #pragma unroll
        for (int i = 0; i < 2; ++i) {
            int m = m0 + tm + i;
            if (m >= M) continue;
            #pragma unroll
            for (int j = 0; j < 4; ++j) {
                int n = n0 + tn + j;
                if (n >= N) continue;
                float v = acc[i][j];
                if (EPI == 1) { v += bias[n]; v = (v > 20.f) ? v : log1pf(__expf(v)); }
                C[(size_t)m * ldc + n] = v;
            }
        }
    }
}

// ============================================================================
// 64x64 tile GEMM with 4x4 micro-tile, CT store:  C^T[n][m] = A@W^T
//   For in_proj (M=3184, N=1024, K=256): 16 FMA per 2 ds_read_b128.
// ============================================================================
__global__ __launch_bounds__(256) void gemm64_ct_kernel(
    const float* __restrict__ A, int lda,
    const float* __restrict__ W, int K,
    float* __restrict__ C, int ldc, int M, int N)
{
    __shared__ __align__(16) float As[32][68];
    __shared__ __align__(16) float Ws[32][68];
    const int m0 = blockIdx.x * 64, n0 = blockIdx.y * 64;
    const int tid = threadIdx.x;
    const int tm = (tid & 15) * 4, tn = (tid >> 4) * 4;
    float acc[4][4];
    #pragma unroll
    for (int i = 0; i < 4; ++i)
        #pragma unroll
        for (int j = 0; j < 4; ++j) acc[i][j] = 0.f;

    for (int k0 = 0; k0 < K; k0 += 32) {
        __syncthreads();
        #pragma unroll
        for (int f = tid; f < 512; f += 256) {
            int m = f >> 3, kq = f & 7;
            float4 v = make_float4(0.f, 0.f, 0.f, 0.f);
            if (m0 + m < M) v = *(const float4*)(A + (size_t)(m0 + m) * lda + k0 + 4 * kq);
            As[4*kq+0][m] = v.x; As[4*kq+1][m] = v.y;
            As[4*kq+2][m] = v.z; As[4*kq+3][m] = v.w;
        }
        #pragma unroll
        for (int f = tid; f < 512; f += 256) {
            int n = f >> 3, kq = f & 7;
            float4 v = make_float4(0.f, 0.f, 0.f, 0.f);
            if (n0 + n < N) v = *(const float4*)(W + (size_t)(n0 + n) * K + k0 + 4 * kq);
            Ws[4*kq+0][n] = v.x; Ws[4*kq+1][n] = v.y;
            Ws[4*kq+2][n] = v.z; Ws[4*kq+3][n] = v.w;
        }
        __syncthreads();
        #pragma unroll
        for (int kk = 0; kk < 32; ++kk) {
            float4 a = *(const float4*)&As[kk][tm];
            float4 b = *(const float4*)&Ws[kk][tn];
            float av[4] = {a.x, a.y, a.z, a.w};
            float bv[4] = {b.x, b.y, b.z, b.w};
            #pragma unroll
            for (int i = 0; i < 4; ++i)
                #pragma unroll
                for (int j = 0; j < 4; ++j)
                    acc[i][j] = fmaf(av[i], bv[j], acc[i][j]);
        }
    }
    #pragma unroll
    for (int j = 0; j < 4; ++j) {
        int n = n0 + tn + j;
        if (n >= N) continue;
        int m = m0 + tm;
        if (m + 3 < M) {
            float4 st = make_float4(acc[0][j], acc[1][j], acc[2][j], acc[3][j]);
            *(float4*)(C + (size_t)n * ldc + m) = st;
        } else {
            #pragma unroll
            for (int i = 0; i < 4; ++i)
                if (m + i < M) C[(size_t)n * ldc + m + i] = acc[i][j];
        }
    }
}

// ============================================================================
// img embed GEMM partials: epart[z][b*196+p][d] = sum_{k in split z} img*W
// ============================================================================
__global__ __launch_bounds__(256) void embed_img_kernel(
    fp32p img, fp32p pi_w, float* __restrict__ epart)
{
    __shared__ __align__(16) float As[28][36];   // [k][p]
    __shared__ __align__(16) float Ws[28][68];   // [k][d]
    const int b  = blockIdx.x / 7;
    const int p0 = (blockIdx.x % 7) * 32;
    const int n0 = blockIdx.y * 64;
    const int tid = threadIdx.x;
    const int tm = (tid & 15) * 2;
    const int tn = (tid >> 4) * 4;
    const int k0s = blockIdx.z * 784;

    float acc[2][4];
    #pragma unroll
    for (int i = 0; i < 2; ++i)
        #pragma unroll
        for (int j = 0; j < 4; ++j) acc[i][j] = 0.f;

    const float* imgb = img + (size_t)b * KIMG * LIMG;

    for (int k0 = k0s; k0 < k0s + 784; k0 += 28) {
        __syncthreads();
        for (int f = tid; f < 28 * 8; f += 256) {
            int kk = f >> 3, pq = f & 7;
            int p = p0 + 4 * pq;
            float4 v = make_float4(0.f, 0.f, 0.f, 0.f);
            if (p < LIMG) v = *(const float4*)(imgb + (size_t)(k0 + kk) * LIMG + p);
            *(float4*)&As[kk][4 * pq] = v;
        }
        for (int f = tid; f < 64 * 7; f += 256) {
            int n = f / 7, kq = f % 7;
            float4 v = *(const float4*)(pi_w + (size_t)(n0 + n) * KIMG + k0 + 4 * kq);
            Ws[4*kq+0][n] = v.x; Ws[4*kq+1][n] = v.y;
            Ws[4*kq+2][n] = v.z; Ws[4*kq+3][n] = v.w;
        }
        __syncthreads();
        #pragma unroll
        for (int kk = 0; kk < 28; ++kk) {
            float2 a = *(const float2*)&As[kk][tm];
            float4 bb = *(const float4*)&Ws[kk][tn];
            float av[2] = {a.x, a.y};
            float bv[4] = {bb.x, bb.y, bb.z, bb.w};
            #pragma unroll
            for (int i = 0; i < 2; ++i)
                #pragma unroll
                for (int j = 0; j < 4; ++j)
                    acc[i][j] = fmaf(av[i], bv[j], acc[i][j]);
        }
    }

    float* ep = epart + (size_t)blockIdx.z * N_IMG * D_MODEL;
    #pragma unroll
    for (int i = 0; i < 2; ++i) {
        int p = p0 + tm + i;
        if (p >= LIMG) continue;
        float4 o = make_float4(acc[i][0], acc[i][1], acc[i][2], acc[i][3]);
        *(float4*)(ep + ((size_t)b * LIMG + p) * D_MODEL + n0 + tn) = o;
    }
}

// img finish: seq[b][1+p][d] = ep0 + ep1 + pi_b[d] + PE(1+p, d)
__global__ __launch_bounds__(256) void img_finish_kernel(
    const float* __restrict__ epart, fp32p pi_b, float* __restrict__ seq)
{
    int idx = (blockIdx.x * 256 + threadIdx.x) * 4;
    int d0  = idx & (D_MODEL - 1);
    int row = idx >> 8;
    int b = row / LIMG, p = row % LIMG;
    int l = p + 1;

    float4 a = *(const float4*)(epart + idx);
    float4 c = *(const float4*)(epart + (size_t)N_IMG * D_MODEL + idx);
    float4 bb = *(const float4*)(pi_b + d0);

    const float cpe = -9.210340371976184f / 256.0f;
    float diva = __expf((float)d0 * cpe);
    float divb = __expf((float)(d0 + 2) * cpe);
    float4 o;
    o.x = a.x + c.x + bb.x + sinf((float)l * diva);
    o.y = a.y + c.y + bb.y + cosf((float)l * diva);
    o.z = a.z + c.z + bb.z + sinf((float)l * divb);
    o.w = a.w + c.w + bb.w + cosf((float)l * divb);
    *(float4*)(seq + ((size_t)b * LSEQ + l) * D_MODEL + d0) = o;
}

// out finish: d_out = seq + op0 + op1
__global__ __launch_bounds__(256) void out_finish_kernel(
    const float* __restrict__ seq, const float* __restrict__ opart,
    float* __restrict__ out)
{
    int idx = (blockIdx.x * 256 + threadIdx.x) * 4;
    float4 s = *(const float4*)(seq + idx);
    float4 a = *(const float4*)(opart + idx);
    float4 c = *(const float4*)(opart + (size_t)N_TOK * D_MODEL + idx);
    float4 o;
    o.x = s.x + a.x + c.x; o.y = s.y + a.y + c.y;
    o.z = s.z + a.z + c.z; o.w = s.w + a.w + c.w;
    *(float4*)(out + idx) = o;
}

// ============================================================================
// text/first/last embed as chunked partial-GEMM (31 chunks x 4 n-tiles)
// ============================================================================
#define KCH 256
__global__ __launch_bounds__(256) void embed3_kernel(
    fp32p text, fp32p firsth, fp32p lasth,
    fp32p pt_w, fp32p pf_w, fp32p pl_w,
    float* __restrict__ ppart)
{
    __shared__ __align__(16) float As[32][20];   // [k][m], 16 tokens
    __shared__ __align__(16) float Ws[32][68];   // [k][n]
    const int chunk = blockIdx.x;
    const int n0 = blockIdx.y * 64;
    const float *src, *w; int k0, K;
    if (chunk < 3)       { src = text;   w = pt_w; k0 = chunk*KCH;      K = KTXT; }
    else if (chunk < 17) { src = firsth; w = pf_w; k0 = (chunk-3)*KCH;  K = KHID; }
    else                 { src = lasth;  w = pl_w; k0 = (chunk-17)*KCH; K = KHID; }

    const int tid = threadIdx.x;
    const int tm = (tid & 7) * 2;
    const int tn = (tid >> 3) * 2;
    float acc[2][2] = {{0.f,0.f},{0.f,0.f}};

    for (int ks = 0; ks < KCH; ks += 32) {
        __syncthreads();
        if (tid < 128) {
            int m = tid >> 3, kq = tid & 7;
            float4 v = *(const float4*)(src + (size_t)m*K + k0 + ks + 4*kq);
            As[4*kq+0][m]=v.x; As[4*kq+1][m]=v.y; As[4*kq+2][m]=v.z; As[4*kq+3][m]=v.w;
        }
        for (int f = tid; f < 512; f += 256) {
            int n = f >> 3, kq = f & 7;
            float4 v = *(const float4*)(w + (size_t)(n0+n)*K + k0 + ks + 4*kq);
            Ws[4*kq+0][n]=v.x; Ws[4*kq+1][n]=v.y; Ws[4*kq+2][n]=v.z; Ws[4*kq+3][n]=v.w;
        }
        __syncthreads();
        #pragma unroll
        for (int kk = 0; kk < 32; ++kk) {
            float2 a = *(const float2*)&As[kk][tm];
            float2 b = *(const float2*)&Ws[kk][tn];
            acc[0][0] = fmaf(a.x, b.x, acc[0][0]);
            acc[0][1] = fmaf(a.x, b.y, acc[0][1]);
            acc[1][0] = fmaf(a.y, b.x, acc[1][0]);
            acc[1][1] = fmaf(a.y, b.y, acc[1][1]);
        }
    }
    float* pp = ppart + (size_t)chunk*16*256;
    pp[(size_t)(tm+0)*256 + n0+tn+0] = acc[0][0];
    pp[(size_t)(tm+0)*256 + n0+tn+1] = acc[0][1];
    pp[(size_t)(tm+1)*256 + n0+tn+0] = acc[1][0];
    pp[(size_t)(tm+1)*256 + n0+tn+1] = acc[1][1];
}

// finish: seq[b][l_c][d] = sum_chunks + bias_c[d] + PE(l_c, d);  48 blocks
__global__ __launch_bounds__(256) void embed3_finish_kernel(
    const float* __restrict__ ppart, fp32p pt_b, fp32p pf_b, fp32p pl_b,
    float* __restrict__ seq)
{
    int idx = blockIdx.x*256 + threadIdx.x;   // [0, 48*256)
    int d = idx & 255;
    int bc = idx >> 8;
    int b = bc / 3, c = bc % 3;
    int c0, nch, l; const float* bias;
    if (c == 0)      { c0 = 0;  nch = 3;  l = 0;        bias = pt_b; }
    else if (c == 1) { c0 = 3;  nch = 14; l = LIMG+1;   bias = pf_b; }
    else             { c0 = 17; nch = 14; l = LIMG+2;   bias = pl_b; }
    float s = bias[d];
    for (int ch = 0; ch < nch; ++ch)
        s += ppart[(size_t)(c0+ch)*16*256 + (size_t)b*256 + d];
    const float cpe = -9.210340371976184f / 256.0f;
    float div = __expf((float)(d & ~1) * cpe);
    float ang = (float)l * div;
    s += (d & 1) ? cosf(ang) : sinf(ang);
    seq[((size_t)b*LSEQ + l)*D_MODEL + d] = s;
}

// ============================================================================
// causal conv(4) + silu over transposed layout
// ============================================================================
__global__ __launch_bounds__(256) void conv_t_kernel(
    const float* __restrict__ xz_T, fp32p conv_w, fp32p conv_b,
    float* __restrict__ xs_T)
{
    int m = blockIdx.x * 256 + threadIdx.x;
    if (m >= N_TOK) return;
    int d = blockIdx.y;
    int t = m % LSEQ;
    const float* xr = xz_T + (size_t)d * N_TOK;
    float w0 = conv_w[d*D_CONV + 0], w1 = conv_w[d*D_CONV + 1];
    float w2 = conv_w[d*D_CONV + 2], w3 = conv_w[d*D_CONV + 3];
    float acc = conv_b[d];
    if (t >= 3) {
        acc = fmaf(xr[m-3], w0, acc); acc = fmaf(xr[m-2], w1, acc);
        acc = fmaf(xr[m-1], w2, acc); acc = fmaf(xr[m],   w3, acc);
    } else {
        if (t >= 2) acc = fmaf(xr[m-2], w1, acc);
        if (t >= 1) acc = fmaf(xr[m-1], w2, acc);
        acc = fmaf(xr[m], w3, acc);
    }
    float sig = 1.f / (1.f + __expf(-acc));
    xs_T[(size_t)d * N_TOK + m] = acc * sig;
}

// ============================================================================
// selective scan, deferred-reduce + 4-step unrolled load batching.
// ============================================================================
#define TCH 32

#define SCAN_STEP(DV, XV, BV, CV, TT)                                   \
    {                                                                    \
        float du = (DV) * (XV);                                          \
        float e0 = __expf((DV)*A0), e1 = __expf((DV)*A1);                \
        float e2 = __expf((DV)*A2), e3 = __expf((DV)*A3);                \
        h0 = fmaf(e0, h0, du*(BV).x); h1 = fmaf(e1, h1, du*(BV).y);      \
        h2 = fmaf(e2, h2, du*(BV).z); h3 = fmaf(e3, h3, du*(BV).w);      \
        float p = fmaf(h0, (CV).x, fmaf(h1, (CV).y,                      \
                  fmaf(h2, (CV).z, h3*(CV).w)));                         \
        pw[(TT)*68 + lane] = p;                                          \
    }

__global__ __launch_bounds__(256) void scan_kernel(
    const float* __restrict__ delta_T, const float* __restrict__ xs_T,
    const float* __restrict__ xz_T, const float* __restrict__ dbc_ws,
    fp32p A_log, fp32p Dp, float* __restrict__ y_T)
{
    __shared__ __align__(16) float part[4][TCH][68];  // [wave][t_loc][lane]
    const int wv   = threadIdx.x >> 6;
    const int wid  = blockIdx.x*4 + wv;               // 4096 waves
    const int lane = threadIdx.x & 63;
    const int b  = wid >> 8;
    const int dp = wid & 255;
    const int sl = lane & 31;
    const int ch = lane >> 5;
    const int d  = dp*2 + ch;

    float4 Av = *(const float4*)(A_log + (size_t)d*D_STATE + 4*sl);
    const float A0 = -__expf(Av.x), A1 = -__expf(Av.y);
    const float A2 = -__expf(Av.z), A3 = -__expf(Av.w);

    const float* dl  = delta_T + (size_t)d*N_TOK + b*LSEQ;
    const float* xl  = xs_T    + (size_t)d*N_TOK + b*LSEQ;
    const float* dbc = dbc_ws  + (size_t)b*LSEQ*272 + DT_RANK + 4*sl;
    float* pw = &part[wv][0][0];

    const float Dr = Dp[d];
    const float* zr = xz_T + (size_t)(D_INNER + d)*N_TOK + b*LSEQ;
    float*       yr = y_T  + (size_t)d*N_TOK + b*LSEQ;

    float h0 = 0.f, h1 = 0.f, h2 = 0.f, h3 = 0.f;

    for (int t0 = 0; t0 < LSEQ; t0 += TCH) {
        const int tc = (LSEQ - t0 < TCH) ? (LSEQ - t0) : TCH;
        int tt = 0;
        for (; tt + 4 <= tc; tt += 4) {
            const int t = t0 + tt;
            // batch all loads for 4 steps up front (latency amortization)
            float d0v = dl[t],   d1v = dl[t+1], d2v = dl[t+2], d3v = dl[t+3];
            float x0v = xl[t],   x1v = xl[t+1], x2v = xl[t+2], x3v = xl[t+3];
            const float* r0 = dbc + (size_t)t*272;
            float4 B0 = *(const float4*)(r0);
            float4 C0 = *(const float4*)(r0 + D_STATE);
            float4 B1 = *(const float4*)(r0 + 272);
            float4 C1 = *(const float4*)(r0 + 272 + D_STATE);
            float4 B2 = *(const float4*)(r0 + 544);
            float4 C2 = *(const float4*)(r0 + 544 + D_STATE);
            float4 B3 = *(const float4*)(r0 + 816);
            float4 C3 = *(const float4*)(r0 + 816 + D_STATE);
            SCAN_STEP(d0v, x0v, B0, C0, tt+0)
            SCAN_STEP(d1v, x1v, B1, C1, tt+1)
            SCAN_STEP(d2v, x2v, B2, C2, tt+2)
            SCAN_STEP(d3v, x3v, B3, C3, tt+3)
        }
        for (; tt < tc; ++tt) {
            const int t = t0 + tt;
            float dv = dl[t], xv = xl[t];
            const float* r = dbc + (size_t)t*272;
            float4 Bv = *(const float4*)(r);
            float4 Cv = *(const float4*)(r + D_STATE);
            SCAN_STEP(dv, xv, Bv, Cv, tt)
        }
        // chunk reduce: lane -> (rc=ch, t_loc=sl); in-wave DS ops in-order
        if (sl < tc) {
            const float* pr = pw + sl*68 + ch*32;
            float s0 = 0.f, s1 = 0.f;
            #pragma unroll
            for (int k = 0; k < 32; k += 8) {
                float4 v0 = *(const float4*)(pr + k);
                float4 v1 = *(const float4*)(pr + k + 4);
                s0 += (v0.x + v0.y) + (v0.z + v0.w);
                s1 += (v1.x + v1.y) + (v1.z + v1.w);
            }
            float sum = s0 + s1;
            const int t = t0 + sl;
            float xv = xl[t], zv = zr[t];
            float y = fmaf(xv, Dr, sum);
            yr[t] = y * (zv / (1.f + __expf(-zv)));
        }
    }
}

extern "C" void kernel_launch(void* const* d_in, const int* in_sizes, int n_in,
                              void* d_out, int out_size, void* d_ws, size_t ws_size,
                              hipStream_t stream)
{
    fp32p text   = (fp32p)d_in[0];
    fp32p img    = (fp32p)d_in[1];
    fp32p firsth = (fp32p)d_in[2];
    fp32p lasth  = (fp32p)d_in[3];
    fp32p pt_w   = (fp32p)d_in[4];
    fp32p pt_b   = (fp32p)d_in[5];
    fp32p pi_w   = (fp32p)d_in[6];
    fp32p pi_b   = (fp32p)d_in[7];
    fp32p pf_w   = (fp32p)d_in[8];
    fp32p pf_b   = (fp32p)d_in[9];
    fp32p pl_w   = (fp32p)d_in[10];
    fp32p pl_b   = (fp32p)d_in[11];
    fp32p inp_w  = (fp32p)d_in[12];
    fp32p conv_w = (fp32p)d_in[13];
    fp32p conv_b = (fp32p)d_in[14];
    fp32p xp_w   = (fp32p)d_in[15];
    fp32p dt_w   = (fp32p)d_in[16];
    fp32p dt_b   = (fp32p)d_in[17];
    fp32p A_log  = (fp32p)d_in[18];
    fp32p Dp     = (fp32p)d_in[19];
    fp32p out_w  = (fp32p)d_in[20];

    float* ws      = (float*)d_ws;
    float* seq     = ws;                                   // 3184*256
    float* xz_T    = seq     + (size_t)N_TOK*D_MODEL;      // 1024*3184 (+pad)
    float* xs_T    = xz_T    + (size_t)1024*N_TOK + 16;    // 512*3184 (+pad)
    float* dbc_ws  = xs_T    + (size_t)D_INNER*N_TOK + 16; // 3184*272
    float* delta_T = dbc_ws  + (size_t)N_TOK*272;          // 512*3184 (+pad)
    float* y_T     = delta_T + (size_t)D_INNER*N_TOK + 16; // 512*3184 (+pad)
    float* epart   = y_T     + (size_t)D_INNER*N_TOK + 16; // 2*3136*256
    float* opart   = epart   + (size_t)2*N_IMG*D_MODEL;    // 2*3184*256
    float* ppart   = opart   + (size_t)2*N_TOK*D_MODEL;    // 31*16*256

    // 1. embeddings
    embed3_kernel<<<dim3(31, 4), 256, 0, stream>>>(
        text, firsth, lasth, pt_w, pf_w, pl_w, ppart);
    embed3_finish_kernel<<<48, 256, 0, stream>>>(ppart, pt_b, pf_b, pl_b, seq);
    embed_img_kernel<<<dim3(BATCH*7, 4, 2), 256, 0, stream>>>(img, pi_w, epart);
    img_finish_kernel<<<N_IMG*D_MODEL/1024, 256, 0, stream>>>(epart, pi_b, seq);

    // 2. in_proj: (3184 x 256) @ (1024 x 256)^T -> xz_T [1024][3184], 64x64 tiles
    gemm64_ct_kernel<<<dim3(50, 16), 256, 0, stream>>>(
        seq, D_MODEL, inp_w, D_MODEL, xz_T, N_TOK, N_TOK, 1024);

    // 3. conv + silu over [d][m]
    conv_t_kernel<<<dim3(13, D_INNER), 256, 0, stream>>>(xz_T, conv_w, conv_b, xs_T);

    // 4. x_proj: A = xs_T (K-major), -> dbc token-major [m][272]
    gemm_kernel<32, 0, 1, 0><<<dim3(100, 5), 256, 0, stream>>>(
        xs_T, N_TOK, xp_w, D_INNER, dbc_ws, 272, N_TOK, 272, nullptr);

    // 5. dt_proj + softplus: -> delta_T [512][3184]
    gemm_kernel<16, 1, 0, 1><<<dim3(100, 8), 256, 0, stream>>>(
        dbc_ws, 272, dt_w, DT_RANK, delta_T, N_TOK, N_TOK, D_INNER, dt_b);

    // 6. scan (4096 waves, 2 channels/wave), deferred LDS reduce, unroll-4
    scan_kernel<<<BATCH*D_INNER/8, 256, 0, stream>>>(
        delta_T, xs_T, xz_T, dbc_ws, A_log, Dp, y_T);

    // 7. out_proj: A = y_T (K-major), K-split 2 -> partials; finish adds resid
    gemm_kernel<32, 0, 1, 0><<<dim3(100, 4, 2), 256, 0, stream>>>(
        y_T, N_TOK, out_w, D_INNER, opart, D_MODEL, N_TOK, D_MODEL, nullptr);
    out_finish_kernel<<<N_TOK*D_MODEL/1024, 256, 0, stream>>>(seq, opart, (float*)d_out);
}

// Round 12
// 358.772 us; speedup vs baseline: 4.8067x; 1.0624x over previous
//
#include <hip/hip_runtime.h>
#include <hip/hip_bf16.h>
#include <math.h>

#define D_MODEL 256
#define D_STATE 128
#define D_CONV  4
#define D_INNER 512
#define DT_RANK 16
#define BATCH   16
#define LIMG    196
#define LSEQ    199
#define KTXT    768
#define KIMG    1568
#define KHID    3584
#define N_TOK   (BATCH*LSEQ)     // 3184
#define N_IMG   (BATCH*LIMG)     // 3136

typedef const float* fp32p;

// ============================================================================
// Generic tiled GEMM:  C = A @ W^T   (+ epilogue)
//   TM=32, TN=64, 256 threads, 2x4 micro-tile.
//   AT: A stored K-major; CT: store C transposed; gridDim.z = K-split.
//   EPI: 0 = plain store, 1 = +bias then softplus
// ============================================================================
template<int BK, int EPI, int AT, int CT>
__global__ __launch_bounds__(256) void gemm_kernel(
    const float* __restrict__ A, int lda,
    const float* __restrict__ W, int K,      // W is N x K row-major
    float* __restrict__ C, int ldc,
    int M, int N,
    const float* __restrict__ bias)
{
    __shared__ __align__(16) float As[BK][36];    // [k][m]
    __shared__ __align__(16) float Ws[BK][68];    // [k][n]
    const int m0 = blockIdx.x * 32;
    const int n0 = blockIdx.y * 64;
    const int tid = threadIdx.x;
    const int tm = (tid & 15) * 2;
    const int tn = (tid >> 4) * 4;
    constexpr int KQ = BK / 4;

    const int kper = K / (int)gridDim.z;
    const int k0s = blockIdx.z * kper;
    if (!CT && gridDim.z > 1) C += (size_t)blockIdx.z * M * ldc;

    float acc[2][4];
    #pragma unroll
    for (int i = 0; i < 2; ++i)
        #pragma unroll
        for (int j = 0; j < 4; ++j) acc[i][j] = 0.f;

    for (int k0 = k0s; k0 < k0s + kper; k0 += BK) {
        __syncthreads();
        if (AT) {
            for (int f = tid; f < 8 * BK; f += 256) {
                int kk = f >> 3, mq = f & 7;
                int m = m0 + 4 * mq;
                float4 v = make_float4(0.f, 0.f, 0.f, 0.f);
                if (m < M) v = *(const float4*)(A + (size_t)(k0 + kk) * lda + m);
                *(float4*)&As[kk][4 * mq] = v;
            }
        } else {
            for (int f = tid; f < 8 * BK; f += 256) {
                int m = f / KQ, kq = f % KQ;
                float4 v = make_float4(0.f, 0.f, 0.f, 0.f);
                if (m0 + m < M) v = *(const float4*)(A + (size_t)(m0 + m) * lda + k0 + 4 * kq);
                As[4*kq+0][m] = v.x; As[4*kq+1][m] = v.y;
                As[4*kq+2][m] = v.z; As[4*kq+3][m] = v.w;
            }
        }
        for (int f = tid; f < 16 * BK; f += 256) {
            int n = f / KQ, kq = f % KQ;
            float4 v = make_float4(0.f, 0.f, 0.f, 0.f);
            if (n0 + n < N) v = *(const float4*)(W + (size_t)(n0 + n) * K + k0 + 4 * kq);
            Ws[4*kq+0][n] = v.x; Ws[4*kq+1][n] = v.y;
            Ws[4*kq+2][n] = v.z; Ws[4*kq+3][n] = v.w;
        }
        __syncthreads();
        #pragma unroll
        for (int kk = 0; kk < BK; ++kk) {
            float2 a = *(const float2*)&As[kk][tm];
            float4 bb = *(const float4*)&Ws[kk][tn];
            float av[2] = {a.x, a.y};
            float bv[4] = {bb.x, bb.y, bb.z, bb.w};
            #pragma unroll
            for (int i = 0; i < 2; ++i)
                #pragma unroll
                for (int j = 0; j < 4; ++j)
                    acc[i][j] = fmaf(av[i], bv[j], acc[i][j]);
        }
    }

    if (CT) {
        int m = m0 + tm;
        #pragma unroll
        for (int j = 0; j < 4; ++j) {
            int n = n0 + tn + j;
            if (n >= N) continue;
            float v0 = acc[0][j], v1 = acc[1][j];
            if (EPI == 1) {
                v0 += bias[n]; v0 = (v0 > 20.f) ? v0 : log1pf(__expf(v0));
                v1 += bias[n]; v1 = (v1 > 20.f) ? v1 : log1pf(__expf(v1));
            }
            if (m + 1 < M) {
                float2 st = make_float2(v0, v1);
                *(float2*)(C + (size_t)n * ldc + m) = st;
            } else if (m < M) {
                C[(size_t)n * ldc + m] = v0;
            }
        }
    } else {
        #pragma unroll
        for (int i = 0; i < 2; ++i) {
            int m = m0 + tm + i;
            if (m >= M) continue;
            #pragma unroll
            for (int j = 0; j < 4; ++j) {
                int n = n0 + tn + j;
                if (n >= N) continue;
                float v = acc[i][j];
                if (EPI == 1) { v += bias[n]; v = (v > 20.f) ? v : log1pf(__expf(v)); }
                C[(size_t)m * ldc + n] = v;
            }
        }
    }
}

// ============================================================================
// 64x64 tile GEMM with 4x4 micro-tile, CT store:  C^T[n][m] = A@W^T
// ============================================================================
__global__ __launch_bounds__(256) void gemm64_ct_kernel(
    const float* __restrict__ A, int lda,
    const float* __restrict__ W, int K,
    float* __restrict__ C, int ldc, int M, int N)
{
    __shared__ __align__(16) float As[32][68];
    __shared__ __align__(16) float Ws[32][68];
    const int m0 = blockIdx.x * 64, n0 = blockIdx.y * 64;
    const int tid = threadIdx.x;
    const int tm = (tid & 15) * 4, tn = (tid >> 4) * 4;
    float acc[4][4];
    #pragma unroll
    for (int i = 0; i < 4; ++i)
        #pragma unroll
        for (int j = 0; j < 4; ++j) acc[i][j] = 0.f;

    for (int k0 = 0; k0 < K; k0 += 32) {
        __syncthreads();
        #pragma unroll
        for (int f = tid; f < 512; f += 256) {
            int m = f >> 3, kq = f & 7;
            float4 v = make_float4(0.f, 0.f, 0.f, 0.f);
            if (m0 + m < M) v = *(const float4*)(A + (size_t)(m0 + m) * lda + k0 + 4 * kq);
            As[4*kq+0][m] = v.x; As[4*kq+1][m] = v.y;
            As[4*kq+2][m] = v.z; As[4*kq+3][m] = v.w;
        }
        #pragma unroll
        for (int f = tid; f < 512; f += 256) {
            int n = f >> 3, kq = f & 7;
            float4 v = make_float4(0.f, 0.f, 0.f, 0.f);
            if (n0 + n < N) v = *(const float4*)(W + (size_t)(n0 + n) * K + k0 + 4 * kq);
            Ws[4*kq+0][n] = v.x; Ws[4*kq+1][n] = v.y;
            Ws[4*kq+2][n] = v.z; Ws[4*kq+3][n] = v.w;
        }
        __syncthreads();
        #pragma unroll
        for (int kk = 0; kk < 32; ++kk) {
            float4 a = *(const float4*)&As[kk][tm];
            float4 b = *(const float4*)&Ws[kk][tn];
            float av[4] = {a.x, a.y, a.z, a.w};
            float bv[4] = {b.x, b.y, b.z, b.w};
            #pragma unroll
            for (int i = 0; i < 4; ++i)
                #pragma unroll
                for (int j = 0; j < 4; ++j)
                    acc[i][j] = fmaf(av[i], bv[j], acc[i][j]);
        }
    }
    #pragma unroll
    for (int j = 0; j < 4; ++j) {
        int n = n0 + tn + j;
        if (n >= N) continue;
        int m = m0 + tm;
        if (m + 3 < M) {
            float4 st = make_float4(acc[0][j], acc[1][j], acc[2][j], acc[3][j]);
            *(float4*)(C + (size_t)n * ldc + m) = st;
        } else {
            #pragma unroll
            for (int i = 0; i < 4; ++i)
                if (m + i < M) C[(size_t)n * ldc + m + i] = acc[i][j];
        }
    }
}

// ============================================================================
// img embed GEMM partials, 64x64 tile, 4x4 micro, K-split 4 (392 K each):
//   epart[z][b*196+p][d] = sum_{k in split z} img[b,k,p] * pi_w[d,k]
//   grid (64, 4, 4): x = b*4 + ptile, y = d-tile, z = K-split
// ============================================================================
__global__ __launch_bounds__(256) void embed_img_kernel(
    fp32p img, fp32p pi_w, float* __restrict__ epart)
{
    __shared__ __align__(16) float As[28][68];   // [k][p]
    __shared__ __align__(16) float Ws[28][68];   // [k][d]
    const int b  = blockIdx.x >> 2;
    const int p0 = (blockIdx.x & 3) * 64;
    const int n0 = blockIdx.y * 64;
    const int k0s = blockIdx.z * 392;            // 4 splits x 392 = 1568 = KIMG
    const int tid = threadIdx.x;
    const int tm = (tid & 15) * 4;
    const int tn = (tid >> 4) * 4;

    float acc[4][4];
    #pragma unroll
    for (int i = 0; i < 4; ++i)
        #pragma unroll
        for (int j = 0; j < 4; ++j) acc[i][j] = 0.f;

    const float* imgb = img + (size_t)b * KIMG * LIMG;

    for (int k0 = k0s; k0 < k0s + 392; k0 += 28) {
        __syncthreads();
        // A tile: 28 k x 64 p, direct float4 (p contiguous)
        #pragma unroll
        for (int f = tid; f < 448; f += 256) {
            int kk = f >> 4, pq = f & 15;
            int p = p0 + 4 * pq;
            float4 v = make_float4(0.f, 0.f, 0.f, 0.f);
            if (p < LIMG) v = *(const float4*)(imgb + (size_t)(k0 + kk) * LIMG + p);
            *(float4*)&As[kk][4 * pq] = v;
        }
        // W tile: 64 d x 28 k, transpose (global-coalesced reads)
        #pragma unroll
        for (int f = tid; f < 448; f += 256) {
            int n = f / 7, kq = f % 7;
            float4 v = *(const float4*)(pi_w + (size_t)(n0 + n) * KIMG + k0 + 4 * kq);
            Ws[4*kq+0][n] = v.x; Ws[4*kq+1][n] = v.y;
            Ws[4*kq+2][n] = v.z; Ws[4*kq+3][n] = v.w;
        }
        __syncthreads();
        #pragma unroll
        for (int kk = 0; kk < 28; ++kk) {
            float4 a = *(const float4*)&As[kk][tm];
            float4 bb = *(const float4*)&Ws[kk][tn];
            float av[4] = {a.x, a.y, a.z, a.w};
            float bv[4] = {bb.x, bb.y, bb.z, bb.w};
            #pragma unroll
            for (int i = 0; i < 4; ++i)
                #pragma unroll
                for (int j = 0; j < 4; ++j)
                    acc[i][j] = fmaf(av[i], bv[j], acc[i][j]);
        }
    }

    float* ep = epart + (size_t)blockIdx.z * N_IMG * D_MODEL;
    #pragma unroll
    for (int i = 0; i < 4; ++i) {
        int p = p0 + tm + i;
        if (p >= LIMG) continue;
        float4 o = make_float4(acc[i][0], acc[i][1], acc[i][2], acc[i][3]);
        *(float4*)(ep + ((size_t)b * LIMG + p) * D_MODEL + n0 + tn) = o;
    }
}

// img finish: seq[b][1+p][d] = ep0+ep1+ep2+ep3 + pi_b[d] + PE(1+p, d)
__global__ __launch_bounds__(256) void img_finish_kernel(
    const float* __restrict__ epart, fp32p pi_b, float* __restrict__ seq)
{
    int idx = (blockIdx.x * 256 + threadIdx.x) * 4;
    int d0  = idx & (D_MODEL - 1);
    int row = idx >> 8;
    int b = row / LIMG, p = row % LIMG;
    int l = p + 1;

    float4 a0 = *(const float4*)(epart + idx);
    float4 a1 = *(const float4*)(epart + (size_t)N_IMG * D_MODEL + idx);
    float4 a2 = *(const float4*)(epart + (size_t)2 * N_IMG * D_MODEL + idx);
    float4 a3 = *(const float4*)(epart + (size_t)3 * N_IMG * D_MODEL + idx);
    float4 bb = *(const float4*)(pi_b + d0);

    const float cpe = -9.210340371976184f / 256.0f;
    float diva = __expf((float)d0 * cpe);
    float divb = __expf((float)(d0 + 2) * cpe);
    float4 o;
    o.x = (a0.x + a1.x) + (a2.x + a3.x) + bb.x + sinf((float)l * diva);
    o.y = (a0.y + a1.y) + (a2.y + a3.y) + bb.y + cosf((float)l * diva);
    o.z = (a0.z + a1.z) + (a2.z + a3.z) + bb.z + sinf((float)l * divb);
    o.w = (a0.w + a1.w) + (a2.w + a3.w) + bb.w + cosf((float)l * divb);
    *(float4*)(seq + ((size_t)b * LSEQ + l) * D_MODEL + d0) = o;
}

// out finish: d_out = seq + op0 + op1
__global__ __launch_bounds__(256) void out_finish_kernel(
    const float* __restrict__ seq, const float* __restrict__ opart,
    float* __restrict__ out)
{
    int idx = (blockIdx.x * 256 + threadIdx.x) * 4;
    float4 s = *(const float4*)(seq + idx);
    float4 a = *(const float4*)(opart + idx);
    float4 c = *(const float4*)(opart + (size_t)N_TOK * D_MODEL + idx);
    float4 o;
    o.x = s.x + a.x + c.x; o.y = s.y + a.y + c.y;
    o.z = s.z + a.z + c.z; o.w = s.w + a.w + c.w;
    *(float4*)(out + idx) = o;
}

// ============================================================================
// text/first/last embed as chunked partial-GEMM (31 chunks x 4 n-tiles)
// ============================================================================
#define KCH 256
__global__ __launch_bounds__(256) void embed3_kernel(
    fp32p text, fp32p firsth, fp32p lasth,
    fp32p pt_w, fp32p pf_w, fp32p pl_w,
    float* __restrict__ ppart)
{
    __shared__ __align__(16) float As[32][20];   // [k][m], 16 tokens
    __shared__ __align__(16) float Ws[32][68];   // [k][n]
    const int chunk = blockIdx.x;
    const int n0 = blockIdx.y * 64;
    const float *src, *w; int k0, K;
    if (chunk < 3)       { src = text;   w = pt_w; k0 = chunk*KCH;      K = KTXT; }
    else if (chunk < 17) { src = firsth; w = pf_w; k0 = (chunk-3)*KCH;  K = KHID; }
    else                 { src = lasth;  w = pl_w; k0 = (chunk-17)*KCH; K = KHID; }

    const int tid = threadIdx.x;
    const int tm = (tid & 7) * 2;
    const int tn = (tid >> 3) * 2;
    float acc[2][2] = {{0.f,0.f},{0.f,0.f}};

    for (int ks = 0; ks < KCH; ks += 32) {
        __syncthreads();
        if (tid < 128) {
            int m = tid >> 3, kq = tid & 7;
            float4 v = *(const float4*)(src + (size_t)m*K + k0 + ks + 4*kq);
            As[4*kq+0][m]=v.x; As[4*kq+1][m]=v.y; As[4*kq+2][m]=v.z; As[4*kq+3][m]=v.w;
        }
        for (int f = tid; f < 512; f += 256) {
            int n = f >> 3, kq = f & 7;
            float4 v = *(const float4*)(w + (size_t)(n0+n)*K + k0 + ks + 4*kq);
            Ws[4*kq+0][n]=v.x; Ws[4*kq+1][n]=v.y; Ws[4*kq+2][n]=v.z; Ws[4*kq+3][n]=v.w;
        }
        __syncthreads();
        #pragma unroll
        for (int kk = 0; kk < 32; ++kk) {
            float2 a = *(const float2*)&As[kk][tm];
            float2 b = *(const float2*)&Ws[kk][tn];
            acc[0][0] = fmaf(a.x, b.x, acc[0][0]);
            acc[0][1] = fmaf(a.x, b.y, acc[0][1]);
            acc[1][0] = fmaf(a.y, b.x, acc[1][0]);
            acc[1][1] = fmaf(a.y, b.y, acc[1][1]);
        }
    }
    float* pp = ppart + (size_t)chunk*16*256;
    pp[(size_t)(tm+0)*256 + n0+tn+0] = acc[0][0];
    pp[(size_t)(tm+0)*256 + n0+tn+1] = acc[0][1];
    pp[(size_t)(tm+1)*256 + n0+tn+0] = acc[1][0];
    pp[(size_t)(tm+1)*256 + n0+tn+1] = acc[1][1];
}

// finish: seq[b][l_c][d] = sum_chunks + bias_c[d] + PE(l_c, d);  48 blocks
__global__ __launch_bounds__(256) void embed3_finish_kernel(
    const float* __restrict__ ppart, fp32p pt_b, fp32p pf_b, fp32p pl_b,
    float* __restrict__ seq)
{
    int idx = blockIdx.x*256 + threadIdx.x;   // [0, 48*256)
    int d = idx & 255;
    int bc = idx >> 8;
    int b = bc / 3, c = bc % 3;
    int c0, nch, l; const float* bias;
    if (c == 0)      { c0 = 0;  nch = 3;  l = 0;        bias = pt_b; }
    else if (c == 1) { c0 = 3;  nch = 14; l = LIMG+1;   bias = pf_b; }
    else             { c0 = 17; nch = 14; l = LIMG+2;   bias = pl_b; }
    float s = bias[d];
    for (int ch = 0; ch < nch; ++ch)
        s += ppart[(size_t)(c0+ch)*16*256 + (size_t)b*256 + d];
    const float cpe = -9.210340371976184f / 256.0f;
    float div = __expf((float)(d & ~1) * cpe);
    float ang = (float)l * div;
    s += (d & 1) ? cosf(ang) : sinf(ang);
    seq[((size_t)b*LSEQ + l)*D_MODEL + d] = s;
}

// ============================================================================
// causal conv(4) + silu over transposed layout
// ============================================================================
__global__ __launch_bounds__(256) void conv_t_kernel(
    const float* __restrict__ xz_T, fp32p conv_w, fp32p conv_b,
    float* __restrict__ xs_T)
{
    int m = blockIdx.x * 256 + threadIdx.x;
    if (m >= N_TOK) return;
    int d = blockIdx.y;
    int t = m % LSEQ;
    const float* xr = xz_T + (size_t)d * N_TOK;
    float w0 = conv_w[d*D_CONV + 0], w1 = conv_w[d*D_CONV + 1];
    float w2 = conv_w[d*D_CONV + 2], w3 = conv_w[d*D_CONV + 3];
    float acc = conv_b[d];
    if (t >= 3) {
        acc = fmaf(xr[m-3], w0, acc); acc = fmaf(xr[m-2], w1, acc);
        acc = fmaf(xr[m-1], w2, acc); acc = fmaf(xr[m],   w3, acc);
    } else {
        if (t >= 2) acc = fmaf(xr[m-2], w1, acc);
        if (t >= 1) acc = fmaf(xr[m-1], w2, acc);
        acc = fmaf(xr[m], w3, acc);
    }
    float sig = 1.f / (1.f + __expf(-acc));
    xs_T[(size_t)d * N_TOK + m] = acc * sig;
}

// ============================================================================
// selective scan, deferred-reduce + 4-step unrolled load batching.
// ============================================================================
#define TCH 32

#define SCAN_STEP(DV, XV, BV, CV, TT)                                   \
    {                                                                    \
        float du = (DV) * (XV);                                          \
        float e0 = __expf((DV)*A0), e1 = __expf((DV)*A1);                \
        float e2 = __expf((DV)*A2), e3 = __expf((DV)*A3);                \
        h0 = fmaf(e0, h0, du*(BV).x); h1 = fmaf(e1, h1, du*(BV).y);      \
        h2 = fmaf(e2, h2, du*(BV).z); h3 = fmaf(e3, h3, du*(BV).w);      \
        float p = fmaf(h0, (CV).x, fmaf(h1, (CV).y,                      \
                  fmaf(h2, (CV).z, h3*(CV).w)));                         \
        pw[(TT)*68 + lane] = p;                                          \
    }

__global__ __launch_bounds__(256) void scan_kernel(
    const float* __restrict__ delta_T, const float* __restrict__ xs_T,
    const float* __restrict__ xz_T, const float* __restrict__ dbc_ws,
    fp32p A_log, fp32p Dp, float* __restrict__ y_T)
{
    __shared__ __align__(16) float part[4][TCH][68];  // [wave][t_loc][lane]
    const int wv   = threadIdx.x >> 6;
    const int wid  = blockIdx.x*4 + wv;               // 4096 waves
    const int lane = threadIdx.x & 63;
    const int b  = wid >> 8;
    const int dp = wid & 255;
    const int sl = lane & 31;
    const int ch = lane >> 5;
    const int d  = dp*2 + ch;

    float4 Av = *(const float4*)(A_log + (size_t)d*D_STATE + 4*sl);
    const float A0 = -__expf(Av.x), A1 = -__expf(Av.y);
    const float A2 = -__expf(Av.z), A3 = -__expf(Av.w);

    const float* dl  = delta_T + (size_t)d*N_TOK + b*LSEQ;
    const float* xl  = xs_T    + (size_t)d*N_TOK + b*LSEQ;
    const float* dbc = dbc_ws  + (size_t)b*LSEQ*272 + DT_RANK + 4*sl;
    float* pw = &part[wv][0][0];

    const float Dr = Dp[d];
    const float* zr = xz_T + (size_t)(D_INNER + d)*N_TOK + b*LSEQ;
    float*       yr = y_T  + (size_t)d*N_TOK + b*LSEQ;

    float h0 = 0.f, h1 = 0.f, h2 = 0.f, h3 = 0.f;

    for (int t0 = 0; t0 < LSEQ; t0 += TCH) {
        const int tc = (LSEQ - t0 < TCH) ? (LSEQ - t0) : TCH;
        int tt = 0;
        for (; tt + 4 <= tc; tt += 4) {
            const int t = t0 + tt;
            float d0v = dl[t],   d1v = dl[t+1], d2v = dl[t+2], d3v = dl[t+3];
            float x0v = xl[t],   x1v = xl[t+1], x2v = xl[t+2], x3v = xl[t+3];
            const float* r0 = dbc + (size_t)t*272;
            float4 B0 = *(const float4*)(r0);
            float4 C0 = *(const float4*)(r0 + D_STATE);
            float4 B1 = *(const float4*)(r0 + 272);
            float4 C1 = *(const float4*)(r0 + 272 + D_STATE);
            float4 B2 = *(const float4*)(r0 + 544);
            float4 C2 = *(const float4*)(r0 + 544 + D_STATE);
            float4 B3 = *(const float4*)(r0 + 816);
            float4 C3 = *(const float4*)(r0 + 816 + D_STATE);
            SCAN_STEP(d0v, x0v, B0, C0, tt+0)
            SCAN_STEP(d1v, x1v, B1, C1, tt+1)
            SCAN_STEP(d2v, x2v, B2, C2, tt+2)
            SCAN_STEP(d3v, x3v, B3, C3, tt+3)
        }
        for (; tt < tc; ++tt) {
            const int t = t0 + tt;
            float dv = dl[t], xv = xl[t];
            const float* r = dbc + (size_t)t*272;
            float4 Bv = *(const float4*)(r);
            float4 Cv = *(const float4*)(r + D_STATE);
            SCAN_STEP(dv, xv, Bv, Cv, tt)
        }
        if (sl < tc) {
            const float* pr = pw + sl*68 + ch*32;
            float s0 = 0.f, s1 = 0.f;
            #pragma unroll
            for (int k = 0; k < 32; k += 8) {
                float4 v0 = *(const float4*)(pr + k);
                float4 v1 = *(const float4*)(pr + k + 4);
                s0 += (v0.x + v0.y) + (v0.z + v0.w);
                s1 += (v1.x + v1.y) + (v1.z + v1.w);
            }
            float sum = s0 + s1;
            const int t = t0 + sl;
            float xv = xl[t], zv = zr[t];
            float y = fmaf(xv, Dr, sum);
            yr[t] = y * (zv / (1.f + __expf(-zv)));
        }
    }
}

extern "C" void kernel_launch(void* const* d_in, const int* in_sizes, int n_in,
                              void* d_out, int out_size, void* d_ws, size_t ws_size,
                              hipStream_t stream)
{
    fp32p text   = (fp32p)d_in[0];
    fp32p img    = (fp32p)d_in[1];
    fp32p firsth = (fp32p)d_in[2];
    fp32p lasth  = (fp32p)d_in[3];
    fp32p pt_w   = (fp32p)d_in[4];
    fp32p pt_b   = (fp32p)d_in[5];
    fp32p pi_w   = (fp32p)d_in[6];
    fp32p pi_b   = (fp32p)d_in[7];
    fp32p pf_w   = (fp32p)d_in[8];
    fp32p pf_b   = (fp32p)d_in[9];
    fp32p pl_w   = (fp32p)d_in[10];
    fp32p pl_b   = (fp32p)d_in[11];
    fp32p inp_w  = (fp32p)d_in[12];
    fp32p conv_w = (fp32p)d_in[13];
    fp32p conv_b = (fp32p)d_in[14];
    fp32p xp_w   = (fp32p)d_in[15];
    fp32p dt_w   = (fp32p)d_in[16];
    fp32p dt_b   = (fp32p)d_in[17];
    fp32p A_log  = (fp32p)d_in[18];
    fp32p Dp     = (fp32p)d_in[19];
    fp32p out_w  = (fp32p)d_in[20];

    float* ws      = (float*)d_ws;
    float* seq     = ws;                                   // 3184*256
    float* xz_T    = seq     + (size_t)N_TOK*D_MODEL;      // 1024*3184 (+pad)
    float* xs_T    = xz_T    + (size_t)1024*N_TOK + 16;    // 512*3184 (+pad)
    float* dbc_ws  = xs_T    + (size_t)D_INNER*N_TOK + 16; // 3184*272
    float* delta_T = dbc_ws  + (size_t)N_TOK*272;          // 512*3184 (+pad)
    float* y_T     = delta_T + (size_t)D_INNER*N_TOK + 16; // 512*3184 (+pad)
    float* epart   = y_T     + (size_t)D_INNER*N_TOK + 16; // 4*3136*256
    float* opart   = epart   + (size_t)4*N_IMG*D_MODEL;    // 2*3184*256
    float* ppart   = opart   + (size_t)2*N_TOK*D_MODEL;    // 31*16*256

    // 1. embeddings
    embed3_kernel<<<dim3(31, 4), 256, 0, stream>>>(
        text, firsth, lasth, pt_w, pf_w, pl_w, ppart);
    embed3_finish_kernel<<<48, 256, 0, stream>>>(ppart, pt_b, pf_b, pl_b, seq);
    embed_img_kernel<<<dim3(BATCH*4, 4, 4), 256, 0, stream>>>(img, pi_w, epart);
    img_finish_kernel<<<N_IMG*D_MODEL/1024, 256, 0, stream>>>(epart, pi_b, seq);

    // 2. in_proj: (3184 x 256) @ (1024 x 256)^T -> xz_T [1024][3184], 64x64 tiles
    gemm64_ct_kernel<<<dim3(50, 16), 256, 0, stream>>>(
        seq, D_MODEL, inp_w, D_MODEL, xz_T, N_TOK, N_TOK, 1024);

    // 3. conv + silu over [d][m]
    conv_t_kernel<<<dim3(13, D_INNER), 256, 0, stream>>>(xz_T, conv_w, conv_b, xs_T);

    // 4. x_proj: A = xs_T (K-major), -> dbc token-major [m][272]
    gemm_kernel<32, 0, 1, 0><<<dim3(100, 5), 256, 0, stream>>>(
        xs_T, N_TOK, xp_w, D_INNER, dbc_ws, 272, N_TOK, 272, nullptr);

    // 5. dt_proj + softplus: -> delta_T [512][3184]
    gemm_kernel<16, 1, 0, 1><<<dim3(100, 8), 256, 0, stream>>>(
        dbc_ws, 272, dt_w, DT_RANK, delta_T, N_TOK, N_TOK, D_INNER, dt_b);

    // 6. scan (4096 waves, 2 channels/wave), deferred LDS reduce, unroll-4
    scan_kernel<<<BATCH*D_INNER/8, 256, 0, stream>>>(
        delta_T, xs_T, xz_T, dbc_ws, A_log, Dp, y_T);

    // 7. out_proj: A = y_T (K-major), K-split 2 -> partials; finish adds resid
    gemm_kernel<32, 0, 1, 0><<<dim3(100, 4, 2), 256, 0, stream>>>(
        y_T, N_TOK, out_w, D_INNER, opart, D_MODEL, N_TOK, D_MODEL, nullptr);
    out_finish_kernel<<<N_TOK*D_MODEL/1024, 256, 0, stream>>>(seq, opart, (float*)d_out);
}